// Round 1
// baseline (777.169 us; speedup 1.0000x reference)
//
#include <hip/hip_runtime.h>

#define N_NODES 100000
#define F1 128      // layer1 in features & out features (4 heads * 32)
#define HID 32
#define HEADS 4
#define NCLS 64

// ---------------------------------------------------------------------------
// Edge dtype probe: reference declares int64 edge_index, but harness may hand
// us int32. If the buffer is int64 (little-endian, values < 2^31), every odd
// int32 word is 0. Probability of false positive on real int32 edge data:
// (1e-5)^64 ~ 0.
__global__ void detect_kernel(const int* __restrict__ ei, int* __restrict__ flag) {
    int tid = threadIdx.x;              // 0..63
    int v = ei[2 * tid + 1];
    unsigned long long ball = __ballot(v == 0);
    if (tid == 0) *flag = (ball == ~0ull) ? 1 : 0;
}

__device__ __forceinline__ int load_edge(const int* ei, int is64, long long idx) {
    return is64 ? ei[2 * idx] : ei[idx];
}

// ---------------------------------------------------------------------------
// CSR build: count -> scan (3 kernels) -> fill
__global__ void count_kernel(const int* __restrict__ ei, const int* __restrict__ flag,
                             int* __restrict__ cnt, int E) {
    int e = blockIdx.x * blockDim.x + threadIdx.x;
    if (e >= E) return;
    int is64 = *flag;
    int dst = load_edge(ei, is64, (long long)E + e);
    atomicAdd(&cnt[dst], 1);
}

#define SCAN_BLOCK 1024
__global__ void scanA_kernel(const int* __restrict__ cnt, int* __restrict__ excl,
                             int* __restrict__ bsum, int n) {
    __shared__ int sm[SCAN_BLOCK];
    int tid = threadIdx.x;
    int i = blockIdx.x * SCAN_BLOCK + tid;
    int v = (i < n) ? cnt[i] : 0;
    sm[tid] = v;
    __syncthreads();
    for (int off = 1; off < SCAN_BLOCK; off <<= 1) {
        int t = (tid >= off) ? sm[tid - off] : 0;
        __syncthreads();
        sm[tid] += t;
        __syncthreads();
    }
    if (i < n) excl[i] = sm[tid] - v;
    if (tid == SCAN_BLOCK - 1) bsum[blockIdx.x] = sm[tid];
}

__global__ void scanB_kernel(int* __restrict__ bsum, int nb,
                             int* __restrict__ row_last, int total) {
    __shared__ int sm[128];
    int tid = threadIdx.x;
    int v = (tid < nb) ? bsum[tid] : 0;
    sm[tid] = v;
    __syncthreads();
    for (int off = 1; off < 128; off <<= 1) {
        int t = (tid >= off) ? sm[tid - off] : 0;
        __syncthreads();
        sm[tid] += t;
        __syncthreads();
    }
    if (tid < nb) bsum[tid] = sm[tid] - v;   // exclusive block offsets
    if (tid == 0) *row_last = total;
}

__global__ void scanC_kernel(int* __restrict__ row_ptr, int* __restrict__ fill_ptr,
                             const int* __restrict__ bsum, int n) {
    int i = blockIdx.x * SCAN_BLOCK + threadIdx.x;
    if (i < n) {
        int v = row_ptr[i] + bsum[blockIdx.x];
        row_ptr[i] = v;
        fill_ptr[i] = v;
    }
}

__global__ void fill_kernel(const int* __restrict__ ei, const int* __restrict__ flag,
                            int* __restrict__ fill_ptr, int* __restrict__ col, int E) {
    int e = blockIdx.x * blockDim.x + threadIdx.x;
    if (e >= E) return;
    int is64 = *flag;
    int dst = load_edge(ei, is64, (long long)E + e);
    int src = load_edge(ei, is64, e);
    int p = atomicAdd(&fill_ptr[dst], 1);
    col[p] = src;
}

// ---------------------------------------------------------------------------
// Layer 1 GEMM: h = x @ W1 ([N,128] x [128,128]) fused with attention coeffs
// a_s[n,h] = sum_c h[n,h,c]*att_src[h,c], a_d likewise.
__global__ __launch_bounds__(256) void gemm1_kernel(
        const float* __restrict__ x, const float* __restrict__ W,
        const float* __restrict__ att_s, const float* __restrict__ att_d,
        float* __restrict__ h, float* __restrict__ as_, float* __restrict__ ad_, int n) {
    __shared__ float Wl[F1 * 128];   // 64 KB
    __shared__ float xs[8][F1];      // 4 KB
    for (int i = threadIdx.x; i < F1 * 128; i += 256) Wl[i] = W[i];
    int c = threadIdx.x & 127;
    int sub = threadIdx.x >> 7;      // 0/1 -> owns nodes sub*4 .. sub*4+3
    int head = c >> 5;
    float asv = att_s[c];            // [4][32] flat == channel index
    float adv = att_d[c];
    int niter = (n + 7) >> 3;
    for (int it = blockIdx.x; it < niter; it += gridDim.x) {
        int base = it * 8;
        __syncthreads();
        for (int i = threadIdx.x; i < 8 * F1; i += 256) {
            int r = base + (i >> 7);
            xs[i >> 7][i & 127] = (r < n) ? x[(size_t)r * F1 + (i & 127)] : 0.f;
        }
        __syncthreads();
        float a0 = 0.f, a1 = 0.f, a2 = 0.f, a3 = 0.f;
        #pragma unroll 4
        for (int f = 0; f < F1; ++f) {
            float w = Wl[f * 128 + c];
            a0 = fmaf(xs[sub * 4 + 0][f], w, a0);
            a1 = fmaf(xs[sub * 4 + 1][f], w, a1);
            a2 = fmaf(xs[sub * 4 + 2][f], w, a2);
            a3 = fmaf(xs[sub * 4 + 3][f], w, a3);
        }
        float accs[4] = {a0, a1, a2, a3};
        #pragma unroll
        for (int j = 0; j < 4; ++j) {
            int node = base + sub * 4 + j;
            if (node < n) {
                float acc = accs[j];
                h[(size_t)node * 128 + c] = acc;
                float ps = acc * asv, pd = acc * adv;
                #pragma unroll
                for (int off = 16; off; off >>= 1) {
                    ps += __shfl_xor(ps, off);
                    pd += __shfl_xor(pd, off);
                }
                if ((c & 31) == 0) {
                    as_[node * 4 + head] = ps;
                    ad_[node * 4 + head] = pd;
                }
            }
        }
    }
}

// Layer 2 GEMM: h2 = x1 @ W2 ([N,128] x [128,64]) fused with scalar attn coeffs
__global__ __launch_bounds__(256) void gemm2_kernel(
        const float* __restrict__ x, const float* __restrict__ W,
        const float* __restrict__ att_s, const float* __restrict__ att_d,
        float* __restrict__ h, float* __restrict__ as_, float* __restrict__ ad_, int n) {
    __shared__ float Wl[F1 * NCLS];  // 32 KB
    __shared__ float xs[8][F1];      // 4 KB
    for (int i = threadIdx.x; i < F1 * NCLS; i += 256) Wl[i] = W[i];
    int c = threadIdx.x & 63;
    int sub = threadIdx.x >> 6;      // 0..3 -> owns nodes sub*2, sub*2+1
    float asv = att_s[c];
    float adv = att_d[c];
    int niter = (n + 7) >> 3;
    for (int it = blockIdx.x; it < niter; it += gridDim.x) {
        int base = it * 8;
        __syncthreads();
        for (int i = threadIdx.x; i < 8 * F1; i += 256) {
            int r = base + (i >> 7);
            xs[i >> 7][i & 127] = (r < n) ? x[(size_t)r * F1 + (i & 127)] : 0.f;
        }
        __syncthreads();
        float a0 = 0.f, a1 = 0.f;
        #pragma unroll 4
        for (int f = 0; f < F1; ++f) {
            float w = Wl[f * NCLS + c];
            a0 = fmaf(xs[sub * 2 + 0][f], w, a0);
            a1 = fmaf(xs[sub * 2 + 1][f], w, a1);
        }
        float accs[2] = {a0, a1};
        #pragma unroll
        for (int j = 0; j < 2; ++j) {
            int node = base + sub * 2 + j;
            if (node < n) {
                float acc = accs[j];
                h[(size_t)node * NCLS + c] = acc;
                float ps = acc * asv, pd = acc * adv;
                #pragma unroll
                for (int off = 32; off; off >>= 1) {
                    ps += __shfl_xor(ps, off);
                    pd += __shfl_xor(pd, off);
                }
                if (c == 0) { as_[node] = ps; ad_[node] = pd; }
            }
        }
    }
}

// ---------------------------------------------------------------------------
// Aggregation layer 1: one wave per dst node. lane owns channels {l, l+64}
// (heads l/32 and l/32+2). Softmax without max-subtraction (|e| <~ 3, safe);
// self-loop handled inline (CSR holds only real edges).
__global__ __launch_bounds__(256) void agg1_kernel(
        const float* __restrict__ h, const float* __restrict__ as_,
        const float* __restrict__ ad_, const int* __restrict__ row_ptr,
        const int* __restrict__ col, const float* __restrict__ bias,
        float* __restrict__ out, int n) {
    int wid = (blockIdx.x * 256 + threadIdx.x) >> 6;
    int lane = threadIdx.x & 63;
    if (wid >= n) return;
    int node = wid;
    int h0 = lane >> 5;              // head of channel `lane`
    float ad0 = ad_[node * 4 + h0];
    float ad1 = ad_[node * 4 + h0 + 2];
    float s0, s1, acc0, acc1;
    {   // self loop
        float e0 = as_[node * 4 + h0] + ad0;     e0 = fmaxf(e0, 0.2f * e0);
        float e1 = as_[node * 4 + h0 + 2] + ad1; e1 = fmaxf(e1, 0.2f * e1);
        float w0 = __expf(e0), w1 = __expf(e1);
        s0 = w0; s1 = w1;
        const float* hr = h + (size_t)node * 128;
        acc0 = w0 * hr[lane];
        acc1 = w1 * hr[lane + 64];
    }
    int beg = row_ptr[node], end = row_ptr[node + 1];
    for (int p = beg; p < end; ++p) {
        int src = col[p];
        float e0 = as_[src * 4 + h0] + ad0;      e0 = fmaxf(e0, 0.2f * e0);
        float e1 = as_[src * 4 + h0 + 2] + ad1;  e1 = fmaxf(e1, 0.2f * e1);
        float w0 = __expf(e0), w1 = __expf(e1);
        s0 += w0; s1 += w1;
        const float* hr = h + (size_t)src * 128;
        acc0 = fmaf(w0, hr[lane], acc0);
        acc1 = fmaf(w1, hr[lane + 64], acc1);
    }
    out[(size_t)node * 128 + lane]      = acc0 / (s0 + 1e-16f) + bias[lane];
    out[(size_t)node * 128 + 64 + lane] = acc1 / (s1 + 1e-16f) + bias[lane + 64];
}

// Aggregation layer 2: one wave per dst node, 64 channels, single head.
__global__ __launch_bounds__(256) void agg2_kernel(
        const float* __restrict__ h, const float* __restrict__ as_,
        const float* __restrict__ ad_, const int* __restrict__ row_ptr,
        const int* __restrict__ col, const float* __restrict__ bias,
        float* __restrict__ out, int n) {
    int wid = (blockIdx.x * 256 + threadIdx.x) >> 6;
    int lane = threadIdx.x & 63;
    if (wid >= n) return;
    int node = wid;
    float ad = ad_[node];
    float e = as_[node] + ad; e = fmaxf(e, 0.2f * e);
    float w = __expf(e);
    float s = w;
    float acc = w * h[(size_t)node * NCLS + lane];
    int beg = row_ptr[node], end = row_ptr[node + 1];
    for (int p = beg; p < end; ++p) {
        int src = col[p];
        float e2 = as_[src] + ad; e2 = fmaxf(e2, 0.2f * e2);
        float w2 = __expf(e2);
        s += w2;
        acc = fmaf(w2, h[(size_t)src * NCLS + lane], acc);
    }
    out[(size_t)node * NCLS + lane] = acc / (s + 1e-16f) + bias[lane];
}

// ---------------------------------------------------------------------------
extern "C" void kernel_launch(void* const* d_in, const int* in_sizes, int n_in,
                              void* d_out, int out_size, void* d_ws, size_t ws_size,
                              hipStream_t stream) {
    const float* inp   = (const float*)d_in[0];
    const int*   ei    = (const int*)d_in[1];
    const float* W1    = (const float*)d_in[2];
    const float* atts1 = (const float*)d_in[3];
    const float* attd1 = (const float*)d_in[4];
    const float* bias1 = (const float*)d_in[5];
    const float* W2    = (const float*)d_in[6];
    const float* atts2 = (const float*)d_in[7];
    const float* attd2 = (const float*)d_in[8];
    const float* bias2 = (const float*)d_in[9];
    float* out = (float*)d_out;

    const int N = N_NODES;
    const int E = in_sizes[1] / 2;

    // workspace layout (h2 aliases h1; as2/ad2 alias as1/ad1)
    float* ws  = (float*)d_ws;
    float* h1  = ws;                           // N*128 floats (layer2 reuses as N*64)
    float* x1  = h1 + (size_t)N * 128;         // N*128
    float* as1 = x1 + (size_t)N * 128;         // N*4
    float* ad1 = as1 + (size_t)N * 4;          // N*4
    int* cnt      = (int*)(ad1 + (size_t)N * 4);  // N
    int* row_ptr  = cnt + N;                      // N+1
    int* fill_ptr = row_ptr + N + 1;              // N
    int* bsum     = fill_ptr + N;                 // 128
    int* flag     = bsum + 128;                   // 1
    int* col      = flag + 1;                     // E

    hipMemsetAsync(cnt, 0, N * sizeof(int), stream);

    detect_kernel<<<1, 64, 0, stream>>>(ei, flag);

    int nb = (N + SCAN_BLOCK - 1) / SCAN_BLOCK;   // 98
    count_kernel<<<(E + 255) / 256, 256, 0, stream>>>(ei, flag, cnt, E);
    scanA_kernel<<<nb, SCAN_BLOCK, 0, stream>>>(cnt, row_ptr, bsum, N);
    scanB_kernel<<<1, 128, 0, stream>>>(bsum, nb, row_ptr + N, E);
    scanC_kernel<<<nb, SCAN_BLOCK, 0, stream>>>(row_ptr, fill_ptr, bsum, N);
    fill_kernel<<<(E + 255) / 256, 256, 0, stream>>>(ei, flag, fill_ptr, col, E);

    // layer 1
    gemm1_kernel<<<2048, 256, 0, stream>>>(inp, W1, atts1, attd1, h1, as1, ad1, N);
    agg1_kernel<<<(N + 3) / 4, 256, 0, stream>>>(h1, as1, ad1, row_ptr, col, bias1, x1, N);

    // layer 2
    gemm2_kernel<<<2048, 256, 0, stream>>>(x1, W2, atts2, attd2, h1, as1, ad1, N);
    agg2_kernel<<<(N + 3) / 4, 256, 0, stream>>>(h1, as1, ad1, row_ptr, col, bias2, out, N);
}

// Round 2
// 556.131 us; speedup vs baseline: 1.3975x; 1.3975x over previous
//
#include <hip/hip_runtime.h>

#define N_NODES 100000
#define F1 128
#define NCLS 64

__device__ __forceinline__ unsigned f2bf(float x) {
    unsigned u = __builtin_bit_cast(unsigned, x);
    u += 0x7fff + ((u >> 16) & 1);
    return u >> 16;
}
__device__ __forceinline__ float bflo(unsigned u) {
    return __builtin_bit_cast(float, u << 16);
}
__device__ __forceinline__ float bfhi(unsigned u) {
    return __builtin_bit_cast(float, u & 0xffff0000u);
}

// ---------------------------------------------------------------------------
// Edge dtype probe (int64 vs int32 edge_index)
__global__ void detect_kernel(const int* __restrict__ ei, int* __restrict__ flag) {
    int tid = threadIdx.x;
    int v = ei[2 * tid + 1];
    unsigned long long ball = __ballot(v == 0);
    if (tid == 0) *flag = (ball == ~0ull) ? 1 : 0;
}

__device__ __forceinline__ int load_edge(const int* ei, int is64, long long idx) {
    return is64 ? ei[2 * idx] : ei[idx];
}

// ---------------------------------------------------------------------------
// CSR build: count -> scan -> fill
__global__ void count_kernel(const int* __restrict__ ei, const int* __restrict__ flag,
                             int* __restrict__ cnt, int E) {
    int e = blockIdx.x * blockDim.x + threadIdx.x;
    if (e >= E) return;
    int is64 = *flag;
    int dst = load_edge(ei, is64, (long long)E + e);
    atomicAdd(&cnt[dst], 1);
}

#define SCAN_BLOCK 1024
__global__ void scanA_kernel(const int* __restrict__ cnt, int* __restrict__ excl,
                             int* __restrict__ bsum, int n) {
    __shared__ int sm[SCAN_BLOCK];
    int tid = threadIdx.x;
    int i = blockIdx.x * SCAN_BLOCK + tid;
    int v = (i < n) ? cnt[i] : 0;
    sm[tid] = v;
    __syncthreads();
    for (int off = 1; off < SCAN_BLOCK; off <<= 1) {
        int t = (tid >= off) ? sm[tid - off] : 0;
        __syncthreads();
        sm[tid] += t;
        __syncthreads();
    }
    if (i < n) excl[i] = sm[tid] - v;
    if (tid == SCAN_BLOCK - 1) bsum[blockIdx.x] = sm[tid];
}

__global__ void scanB_kernel(int* __restrict__ bsum, int nb,
                             int* __restrict__ row_last, int total) {
    __shared__ int sm[128];
    int tid = threadIdx.x;
    int v = (tid < nb) ? bsum[tid] : 0;
    sm[tid] = v;
    __syncthreads();
    for (int off = 1; off < 128; off <<= 1) {
        int t = (tid >= off) ? sm[tid - off] : 0;
        __syncthreads();
        sm[tid] += t;
        __syncthreads();
    }
    if (tid < nb) bsum[tid] = sm[tid] - v;
    if (tid == 0) *row_last = total;
}

__global__ void scanC_kernel(int* __restrict__ row_ptr, int* __restrict__ fill_ptr,
                             const int* __restrict__ bsum, int n) {
    int i = blockIdx.x * SCAN_BLOCK + threadIdx.x;
    if (i < n) {
        int v = row_ptr[i] + bsum[blockIdx.x];
        row_ptr[i] = v;
        fill_ptr[i] = v;
    }
}

__global__ void fill_kernel(const int* __restrict__ ei, const int* __restrict__ flag,
                            int* __restrict__ fill_ptr, int* __restrict__ col, int E) {
    int e = blockIdx.x * blockDim.x + threadIdx.x;
    if (e >= E) return;
    int is64 = *flag;
    int dst = load_edge(ei, is64, (long long)E + e);
    int src = load_edge(ei, is64, e);
    int p = atomicAdd(&fill_ptr[dst], 1);
    col[p] = src;
}

// ---------------------------------------------------------------------------
// Layer1 GEMM: [N,128]x[128,128], 2D register tile 4 nodes x 4 channels/thread.
// Epilogue: pack h to bf16 pairs + fused attention-coefficient reduction.
__global__ __launch_bounds__(256) void gemm1_kernel(
        const float* __restrict__ x, const float* __restrict__ W,
        const float* __restrict__ att_s, const float* __restrict__ att_d,
        unsigned* __restrict__ hp, float* __restrict__ as_, float* __restrict__ ad_, int n) {
    __shared__ float xs[32][128];   // 16 KB
    __shared__ float Ws[32][128];   // 16 KB (K-chunk)
    int tid = threadIdx.x;
    int cg = tid & 31, ng = tid >> 5;
    int c0 = cg * 4;
    int base = blockIdx.x * 32;
    for (int i = tid; i < 1024; i += 256) {
        int r = i >> 5, o = (i & 31) * 4;
        float4 v = make_float4(0.f, 0.f, 0.f, 0.f);
        if (base + r < n) v = *(const float4*)&x[(size_t)(base + r) * 128 + o];
        *(float4*)&xs[r][o] = v;
    }
    float acc[4][4] = {};
    for (int fc = 0; fc < 4; ++fc) {
        __syncthreads();
        for (int i = tid; i < 1024; i += 256)
            *(float4*)&Ws[i >> 5][(i & 31) * 4] = *(const float4*)&W[fc * 4096 + i * 4];
        __syncthreads();
        #pragma unroll
        for (int f4 = 0; f4 < 8; ++f4) {
            float4 wf[4], xf[4];
            #pragma unroll
            for (int k = 0; k < 4; ++k) wf[k] = *(float4*)&Ws[f4 * 4 + k][c0];
            #pragma unroll
            for (int j = 0; j < 4; ++j) xf[j] = *(float4*)&xs[ng * 4 + j][fc * 32 + f4 * 4];
            #pragma unroll
            for (int k = 0; k < 4; ++k) {
                #pragma unroll
                for (int j = 0; j < 4; ++j) {
                    float xv = (&xf[j].x)[k];
                    acc[j][0] = fmaf(xv, wf[k].x, acc[j][0]);
                    acc[j][1] = fmaf(xv, wf[k].y, acc[j][1]);
                    acc[j][2] = fmaf(xv, wf[k].z, acc[j][2]);
                    acc[j][3] = fmaf(xv, wf[k].w, acc[j][3]);
                }
            }
        }
    }
    float4 asv = *(const float4*)&att_s[c0];
    float4 adv = *(const float4*)&att_d[c0];
    #pragma unroll
    for (int j = 0; j < 4; ++j) {
        int node = base + ng * 4 + j;   // uniform across the cg-shuffle group
        float ps = acc[j][0] * asv.x + acc[j][1] * asv.y + acc[j][2] * asv.z + acc[j][3] * asv.w;
        float pd = acc[j][0] * adv.x + acc[j][1] * adv.y + acc[j][2] * adv.z + acc[j][3] * adv.w;
        ps += __shfl_xor(ps, 1); ps += __shfl_xor(ps, 2); ps += __shfl_xor(ps, 4);
        pd += __shfl_xor(pd, 1); pd += __shfl_xor(pd, 2); pd += __shfl_xor(pd, 4);
        if (node < n) {
            uint2 pk;
            pk.x = f2bf(acc[j][0]) | (f2bf(acc[j][1]) << 16);
            pk.y = f2bf(acc[j][2]) | (f2bf(acc[j][3]) << 16);
            *(uint2*)&hp[(size_t)node * 64 + cg * 2] = pk;
            if ((cg & 7) == 0) {
                as_[(size_t)node * 4 + (cg >> 3)] = ps;
                ad_[(size_t)node * 4 + (cg >> 3)] = pd;
            }
        }
    }
}

// Layer2 GEMM: [N,128]x[128,64]
__global__ __launch_bounds__(256) void gemm2_kernel(
        const float* __restrict__ x, const float* __restrict__ W,
        const float* __restrict__ att_s, const float* __restrict__ att_d,
        unsigned* __restrict__ hp, float* __restrict__ as_, float* __restrict__ ad_, int n) {
    __shared__ float xs[64][128];   // 32 KB
    __shared__ float Ws[32][64];    // 8 KB
    int tid = threadIdx.x;
    int cg = tid & 15, ng = tid >> 4;
    int c0 = cg * 4;
    int base = blockIdx.x * 64;
    for (int i = tid; i < 2048; i += 256) {
        int r = i >> 5, o = (i & 31) * 4;
        float4 v = make_float4(0.f, 0.f, 0.f, 0.f);
        if (base + r < n) v = *(const float4*)&x[(size_t)(base + r) * 128 + o];
        *(float4*)&xs[r][o] = v;
    }
    float acc[4][4] = {};
    for (int fc = 0; fc < 4; ++fc) {
        __syncthreads();
        for (int i = tid; i < 512; i += 256)
            *(float4*)&Ws[i >> 4][(i & 15) * 4] = *(const float4*)&W[fc * 2048 + i * 4];
        __syncthreads();
        #pragma unroll
        for (int f4 = 0; f4 < 8; ++f4) {
            float4 wf[4], xf[4];
            #pragma unroll
            for (int k = 0; k < 4; ++k) wf[k] = *(float4*)&Ws[f4 * 4 + k][c0];
            #pragma unroll
            for (int j = 0; j < 4; ++j) xf[j] = *(float4*)&xs[ng * 4 + j][fc * 32 + f4 * 4];
            #pragma unroll
            for (int k = 0; k < 4; ++k) {
                #pragma unroll
                for (int j = 0; j < 4; ++j) {
                    float xv = (&xf[j].x)[k];
                    acc[j][0] = fmaf(xv, wf[k].x, acc[j][0]);
                    acc[j][1] = fmaf(xv, wf[k].y, acc[j][1]);
                    acc[j][2] = fmaf(xv, wf[k].z, acc[j][2]);
                    acc[j][3] = fmaf(xv, wf[k].w, acc[j][3]);
                }
            }
        }
    }
    float4 asv = *(const float4*)&att_s[c0];
    float4 adv = *(const float4*)&att_d[c0];
    #pragma unroll
    for (int j = 0; j < 4; ++j) {
        int node = base + ng * 4 + j;
        float ps = acc[j][0] * asv.x + acc[j][1] * asv.y + acc[j][2] * asv.z + acc[j][3] * asv.w;
        float pd = acc[j][0] * adv.x + acc[j][1] * adv.y + acc[j][2] * adv.z + acc[j][3] * adv.w;
        ps += __shfl_xor(ps, 1); ps += __shfl_xor(ps, 2);
        ps += __shfl_xor(ps, 4); ps += __shfl_xor(ps, 8);
        pd += __shfl_xor(pd, 1); pd += __shfl_xor(pd, 2);
        pd += __shfl_xor(pd, 4); pd += __shfl_xor(pd, 8);
        if (node < n) {
            uint2 pk;
            pk.x = f2bf(acc[j][0]) | (f2bf(acc[j][1]) << 16);
            pk.y = f2bf(acc[j][2]) | (f2bf(acc[j][3]) << 16);
            *(uint2*)&hp[(size_t)node * 32 + cg * 2] = pk;
            if (cg == 0) { as_[node] = ps; ad_[node] = pd; }
        }
    }
}

// ---------------------------------------------------------------------------
// Aggregation layer1: wave per dst node, lane owns channels (2l, 2l+1),
// bf16-packed gather (256 B/edge), 4-edge software pipeline.
__global__ __launch_bounds__(256) void agg1_kernel(
        const unsigned* __restrict__ hp, const float* __restrict__ as_,
        const float* __restrict__ ad_, const int* __restrict__ row_ptr,
        const int* __restrict__ col, const float* __restrict__ bias,
        float* __restrict__ out, int n) {
    int wid = (blockIdx.x * 256 + threadIdx.x) >> 6;
    int lane = threadIdx.x & 63;
    if (wid >= n) return;
    int node = wid;
    int head = lane >> 4;               // channel 2l -> head (2l)>>5 = l>>4
    float adv = ad_[(size_t)node * 4 + head];
    float e = as_[(size_t)node * 4 + head] + adv;
    e = fmaxf(e, 0.2f * e);
    float w = __expf(e);
    float s = w;
    unsigned u = hp[(size_t)node * 64 + lane];
    float acc0 = w * bflo(u), acc1 = w * bfhi(u);
    int beg = row_ptr[node], end = row_ptr[node + 1];
    for (int p = beg; p < end; p += 4) {
        int m = end - p; if (m > 4) m = 4;
        int srcs[4]; unsigned us[4]; float as4[4];
        #pragma unroll
        for (int i = 0; i < 4; ++i) srcs[i] = col[p + (i < m ? i : 0)];
        #pragma unroll
        for (int i = 0; i < 4; ++i) us[i] = hp[(size_t)srcs[i] * 64 + lane];
        #pragma unroll
        for (int i = 0; i < 4; ++i) as4[i] = as_[(size_t)srcs[i] * 4 + head];
        #pragma unroll
        for (int i = 0; i < 4; ++i) {
            if (i >= m) break;
            float ee = as4[i] + adv; ee = fmaxf(ee, 0.2f * ee);
            float ww = __expf(ee);
            s += ww;
            acc0 = fmaf(ww, bflo(us[i]), acc0);
            acc1 = fmaf(ww, bfhi(us[i]), acc1);
        }
    }
    float inv = 1.0f / (s + 1e-16f);
    float2 b = *(const float2*)&bias[lane * 2];
    *(float2*)&out[(size_t)node * 128 + lane * 2] =
        make_float2(acc0 * inv + b.x, acc1 * inv + b.y);
}

// Aggregation layer2: wave per dst node, 2 edges/iteration (one per half-wave),
// half-lane owns channels (2w, 2w+1) of 64.
__global__ __launch_bounds__(256) void agg2_kernel(
        const unsigned* __restrict__ hp, const float* __restrict__ as_,
        const float* __restrict__ ad_, const int* __restrict__ row_ptr,
        const int* __restrict__ col, const float* __restrict__ bias,
        float* __restrict__ out, int n) {
    int wid = (blockIdx.x * 256 + threadIdx.x) >> 6;
    int lane = threadIdx.x & 63;
    if (wid >= n) return;
    int node = wid;
    int half = lane >> 5, wrd = lane & 31;
    float adv = ad_[node];
    float s = 0.f, acc0 = 0.f, acc1 = 0.f;
    {
        float e = as_[node] + adv; e = fmaxf(e, 0.2f * e);
        float w = __expf(e);
        if (half == 0) {
            unsigned u = hp[(size_t)node * 32 + wrd];
            s = w; acc0 = w * bflo(u); acc1 = w * bfhi(u);
        }
    }
    int beg = row_ptr[node], end = row_ptr[node + 1];
    for (int p = beg; p < end; p += 4) {
        int q0 = p + half * 2, q1 = q0 + 1;
        int v0 = (q0 < end), v1 = (q1 < end);
        int s0 = col[v0 ? q0 : beg];
        int s1 = col[v1 ? q1 : beg];
        unsigned u0 = hp[(size_t)s0 * 32 + wrd];
        unsigned u1 = hp[(size_t)s1 * 32 + wrd];
        float a0 = as_[s0], a1 = as_[s1];
        if (v0) {
            float ee = a0 + adv; ee = fmaxf(ee, 0.2f * ee);
            float ww = __expf(ee);
            s += ww; acc0 = fmaf(ww, bflo(u0), acc0); acc1 = fmaf(ww, bfhi(u0), acc1);
        }
        if (v1) {
            float ee = a1 + adv; ee = fmaxf(ee, 0.2f * ee);
            float ww = __expf(ee);
            s += ww; acc0 = fmaf(ww, bflo(u1), acc0); acc1 = fmaf(ww, bfhi(u1), acc1);
        }
    }
    s += __shfl_xor(s, 32);
    acc0 += __shfl_xor(acc0, 32);
    acc1 += __shfl_xor(acc1, 32);
    if (half == 0) {
        float inv = 1.0f / (s + 1e-16f);
        float2 b = *(const float2*)&bias[wrd * 2];
        *(float2*)&out[(size_t)node * 64 + wrd * 2] =
            make_float2(acc0 * inv + b.x, acc1 * inv + b.y);
    }
}

// ---------------------------------------------------------------------------
extern "C" void kernel_launch(void* const* d_in, const int* in_sizes, int n_in,
                              void* d_out, int out_size, void* d_ws, size_t ws_size,
                              hipStream_t stream) {
    const float* inp   = (const float*)d_in[0];
    const int*   ei    = (const int*)d_in[1];
    const float* W1    = (const float*)d_in[2];
    const float* atts1 = (const float*)d_in[3];
    const float* attd1 = (const float*)d_in[4];
    const float* bias1 = (const float*)d_in[5];
    const float* W2    = (const float*)d_in[6];
    const float* atts2 = (const float*)d_in[7];
    const float* attd2 = (const float*)d_in[8];
    const float* bias2 = (const float*)d_in[9];
    float* out = (float*)d_out;

    const int N = N_NODES;
    const int E = in_sizes[1] / 2;

    unsigned* h1p = (unsigned*)d_ws;               // N*64 uints (layer2 reuses N*32)
    float* x1  = (float*)(h1p + (size_t)N * 64);   // N*128 f32
    float* as1 = x1 + (size_t)N * 128;             // N*4
    float* ad1 = as1 + (size_t)N * 4;              // N*4
    int* cnt      = (int*)(ad1 + (size_t)N * 4);   // N
    int* row_ptr  = cnt + N;                       // N+1
    int* fill_ptr = row_ptr + N + 1;               // N
    int* bsum     = fill_ptr + N;                  // 128
    int* flag     = bsum + 128;                    // 1
    int* col      = flag + 1;                      // E

    hipMemsetAsync(cnt, 0, N * sizeof(int), stream);
    detect_kernel<<<1, 64, 0, stream>>>(ei, flag);

    int nb = (N + SCAN_BLOCK - 1) / SCAN_BLOCK;
    count_kernel<<<(E + 255) / 256, 256, 0, stream>>>(ei, flag, cnt, E);
    scanA_kernel<<<nb, SCAN_BLOCK, 0, stream>>>(cnt, row_ptr, bsum, N);
    scanB_kernel<<<1, 128, 0, stream>>>(bsum, nb, row_ptr + N, E);
    scanC_kernel<<<nb, SCAN_BLOCK, 0, stream>>>(row_ptr, fill_ptr, bsum, N);
    fill_kernel<<<(E + 255) / 256, 256, 0, stream>>>(ei, flag, fill_ptr, col, E);

    // layer 1
    gemm1_kernel<<<(N + 31) / 32, 256, 0, stream>>>(inp, W1, atts1, attd1, h1p, as1, ad1, N);
    agg1_kernel<<<(N + 3) / 4, 256, 0, stream>>>(h1p, as1, ad1, row_ptr, col, bias1, x1, N);

    // layer 2 (h2p aliases h1p; as2/ad2 alias as1/ad1)
    gemm2_kernel<<<(N + 63) / 64, 256, 0, stream>>>(x1, W2, atts2, attd2, h1p, as1, ad1, N);
    agg2_kernel<<<(N + 3) / 4, 256, 0, stream>>>(h1p, as1, ad1, row_ptr, col, bias2, out, N);
}

// Round 3
// 467.966 us; speedup vs baseline: 1.6607x; 1.1884x over previous
//
#include <hip/hip_runtime.h>

#define N_NODES 100000
#define F1 128
#define NCLS 64

__device__ __forceinline__ unsigned f2bf(float x) {
    unsigned u = __builtin_bit_cast(unsigned, x);
    u += 0x7fff + ((u >> 16) & 1);
    return u >> 16;
}
__device__ __forceinline__ float bflo(unsigned u) {
    return __builtin_bit_cast(float, u << 16);
}
__device__ __forceinline__ float bfhi(unsigned u) {
    return __builtin_bit_cast(float, u & 0xffff0000u);
}

// ---------------------------------------------------------------------------
// Edge dtype probe (int64 vs int32 edge_index)
__global__ void detect_kernel(const int* __restrict__ ei, int* __restrict__ flag) {
    int tid = threadIdx.x;
    int v = ei[2 * tid + 1];
    unsigned long long ball = __ballot(v == 0);
    if (tid == 0) *flag = (ball == ~0ull) ? 1 : 0;
}

__device__ __forceinline__ int load_edge(const int* ei, int is64, long long idx) {
    return is64 ? ei[2 * idx] : ei[idx];
}

// ---------------------------------------------------------------------------
// CSR build: count -> scan -> fill
__global__ void count_kernel(const int* __restrict__ ei, const int* __restrict__ flag,
                             int* __restrict__ cnt, int E) {
    int e = blockIdx.x * blockDim.x + threadIdx.x;
    if (e >= E) return;
    int is64 = *flag;
    int dst = load_edge(ei, is64, (long long)E + e);
    atomicAdd(&cnt[dst], 1);
}

#define SCAN_BLOCK 1024
__global__ void scanA_kernel(const int* __restrict__ cnt, int* __restrict__ excl,
                             int* __restrict__ bsum, int n) {
    __shared__ int sm[SCAN_BLOCK];
    int tid = threadIdx.x;
    int i = blockIdx.x * SCAN_BLOCK + tid;
    int v = (i < n) ? cnt[i] : 0;
    sm[tid] = v;
    __syncthreads();
    for (int off = 1; off < SCAN_BLOCK; off <<= 1) {
        int t = (tid >= off) ? sm[tid - off] : 0;
        __syncthreads();
        sm[tid] += t;
        __syncthreads();
    }
    if (i < n) excl[i] = sm[tid] - v;
    if (tid == SCAN_BLOCK - 1) bsum[blockIdx.x] = sm[tid];
}

__global__ void scanB_kernel(int* __restrict__ bsum, int nb,
                             int* __restrict__ row_last, int total) {
    __shared__ int sm[128];
    int tid = threadIdx.x;
    int v = (tid < nb) ? bsum[tid] : 0;
    sm[tid] = v;
    __syncthreads();
    for (int off = 1; off < 128; off <<= 1) {
        int t = (tid >= off) ? sm[tid - off] : 0;
        __syncthreads();
        sm[tid] += t;
        __syncthreads();
    }
    if (tid < nb) bsum[tid] = sm[tid] - v;
    if (tid == 0) *row_last = total;
}

__global__ void scanC_kernel(int* __restrict__ row_ptr, int* __restrict__ fill_ptr,
                             const int* __restrict__ bsum, int n) {
    int i = blockIdx.x * SCAN_BLOCK + threadIdx.x;
    if (i < n) {
        int v = row_ptr[i] + bsum[blockIdx.x];
        row_ptr[i] = v;
        fill_ptr[i] = v;
    }
}

__global__ void fill_kernel(const int* __restrict__ ei, const int* __restrict__ flag,
                            int* __restrict__ fill_ptr, int* __restrict__ col, int E) {
    int e = blockIdx.x * blockDim.x + threadIdx.x;
    if (e >= E) return;
    int is64 = *flag;
    int dst = load_edge(ei, is64, (long long)E + e);
    int src = load_edge(ei, is64, e);
    int p = atomicAdd(&fill_ptr[dst], 1);
    col[p] = src;
}

// ---------------------------------------------------------------------------
// Layer1 GEMM: [N,128]x[128,128], 2D register tile 4 nodes x 4 channels/thread.
__global__ __launch_bounds__(256) void gemm1_kernel(
        const float* __restrict__ x, const float* __restrict__ W,
        const float* __restrict__ att_s, const float* __restrict__ att_d,
        unsigned* __restrict__ hp, float* __restrict__ as_, float* __restrict__ ad_, int n) {
    __shared__ float xs[32][128];   // 16 KB
    __shared__ float Ws[32][128];   // 16 KB (K-chunk)
    int tid = threadIdx.x;
    int cg = tid & 31, ng = tid >> 5;
    int c0 = cg * 4;
    int base = blockIdx.x * 32;
    for (int i = tid; i < 1024; i += 256) {
        int r = i >> 5, o = (i & 31) * 4;
        float4 v = make_float4(0.f, 0.f, 0.f, 0.f);
        if (base + r < n) v = *(const float4*)&x[(size_t)(base + r) * 128 + o];
        *(float4*)&xs[r][o] = v;
    }
    float acc[4][4] = {};
    for (int fc = 0; fc < 4; ++fc) {
        __syncthreads();
        for (int i = tid; i < 1024; i += 256)
            *(float4*)&Ws[i >> 5][(i & 31) * 4] = *(const float4*)&W[fc * 4096 + i * 4];
        __syncthreads();
        #pragma unroll
        for (int f4 = 0; f4 < 8; ++f4) {
            float4 wf[4], xf[4];
            #pragma unroll
            for (int k = 0; k < 4; ++k) wf[k] = *(float4*)&Ws[f4 * 4 + k][c0];
            #pragma unroll
            for (int j = 0; j < 4; ++j) xf[j] = *(float4*)&xs[ng * 4 + j][fc * 32 + f4 * 4];
            #pragma unroll
            for (int k = 0; k < 4; ++k) {
                #pragma unroll
                for (int j = 0; j < 4; ++j) {
                    float xv = (&xf[j].x)[k];
                    acc[j][0] = fmaf(xv, wf[k].x, acc[j][0]);
                    acc[j][1] = fmaf(xv, wf[k].y, acc[j][1]);
                    acc[j][2] = fmaf(xv, wf[k].z, acc[j][2]);
                    acc[j][3] = fmaf(xv, wf[k].w, acc[j][3]);
                }
            }
        }
    }
    float4 asv = *(const float4*)&att_s[c0];
    float4 adv = *(const float4*)&att_d[c0];
    #pragma unroll
    for (int j = 0; j < 4; ++j) {
        int node = base + ng * 4 + j;
        float ps = acc[j][0] * asv.x + acc[j][1] * asv.y + acc[j][2] * asv.z + acc[j][3] * asv.w;
        float pd = acc[j][0] * adv.x + acc[j][1] * adv.y + acc[j][2] * adv.z + acc[j][3] * adv.w;
        ps += __shfl_xor(ps, 1); ps += __shfl_xor(ps, 2); ps += __shfl_xor(ps, 4);
        pd += __shfl_xor(pd, 1); pd += __shfl_xor(pd, 2); pd += __shfl_xor(pd, 4);
        if (node < n) {
            uint2 pk;
            pk.x = f2bf(acc[j][0]) | (f2bf(acc[j][1]) << 16);
            pk.y = f2bf(acc[j][2]) | (f2bf(acc[j][3]) << 16);
            *(uint2*)&hp[(size_t)node * 64 + cg * 2] = pk;
            if ((cg & 7) == 0) {
                as_[(size_t)node * 4 + (cg >> 3)] = ps;
                ad_[(size_t)node * 4 + (cg >> 3)] = pd;
            }
        }
    }
}

// Layer2 GEMM: [N,128]x[128,64]
__global__ __launch_bounds__(256) void gemm2_kernel(
        const float* __restrict__ x, const float* __restrict__ W,
        const float* __restrict__ att_s, const float* __restrict__ att_d,
        unsigned* __restrict__ hp, float* __restrict__ as_, float* __restrict__ ad_, int n) {
    __shared__ float xs[64][128];   // 32 KB
    __shared__ float Ws[32][64];    // 8 KB
    int tid = threadIdx.x;
    int cg = tid & 15, ng = tid >> 4;
    int c0 = cg * 4;
    int base = blockIdx.x * 64;
    for (int i = tid; i < 2048; i += 256) {
        int r = i >> 5, o = (i & 31) * 4;
        float4 v = make_float4(0.f, 0.f, 0.f, 0.f);
        if (base + r < n) v = *(const float4*)&x[(size_t)(base + r) * 128 + o];
        *(float4*)&xs[r][o] = v;
    }
    float acc[4][4] = {};
    for (int fc = 0; fc < 4; ++fc) {
        __syncthreads();
        for (int i = tid; i < 512; i += 256)
            *(float4*)&Ws[i >> 4][(i & 15) * 4] = *(const float4*)&W[fc * 2048 + i * 4];
        __syncthreads();
        #pragma unroll
        for (int f4 = 0; f4 < 8; ++f4) {
            float4 wf[4], xf[4];
            #pragma unroll
            for (int k = 0; k < 4; ++k) wf[k] = *(float4*)&Ws[f4 * 4 + k][c0];
            #pragma unroll
            for (int j = 0; j < 4; ++j) xf[j] = *(float4*)&xs[ng * 4 + j][fc * 32 + f4 * 4];
            #pragma unroll
            for (int k = 0; k < 4; ++k) {
                #pragma unroll
                for (int j = 0; j < 4; ++j) {
                    float xv = (&xf[j].x)[k];
                    acc[j][0] = fmaf(xv, wf[k].x, acc[j][0]);
                    acc[j][1] = fmaf(xv, wf[k].y, acc[j][1]);
                    acc[j][2] = fmaf(xv, wf[k].z, acc[j][2]);
                    acc[j][3] = fmaf(xv, wf[k].w, acc[j][3]);
                }
            }
        }
    }
    float4 asv = *(const float4*)&att_s[c0];
    float4 adv = *(const float4*)&att_d[c0];
    #pragma unroll
    for (int j = 0; j < 4; ++j) {
        int node = base + ng * 4 + j;
        float ps = acc[j][0] * asv.x + acc[j][1] * asv.y + acc[j][2] * asv.z + acc[j][3] * asv.w;
        float pd = acc[j][0] * adv.x + acc[j][1] * adv.y + acc[j][2] * adv.z + acc[j][3] * adv.w;
        ps += __shfl_xor(ps, 1); ps += __shfl_xor(ps, 2);
        ps += __shfl_xor(ps, 4); ps += __shfl_xor(ps, 8);
        pd += __shfl_xor(pd, 1); pd += __shfl_xor(pd, 2);
        pd += __shfl_xor(pd, 4); pd += __shfl_xor(pd, 8);
        if (node < n) {
            uint2 pk;
            pk.x = f2bf(acc[j][0]) | (f2bf(acc[j][1]) << 16);
            pk.y = f2bf(acc[j][2]) | (f2bf(acc[j][3]) << 16);
            *(uint2*)&hp[(size_t)node * 32 + cg * 2] = pk;
            if (cg == 0) { as_[node] = ps; ad_[node] = pd; }
        }
    }
}

// ---------------------------------------------------------------------------
// Aggregation layer1: wave per dst node, lane owns channels (2l, 2l+1).
// Cooperative col prefetch (one coalesced load per <=64 edges, shfl broadcast)
// + 8-deep independent gather pipeline.
__global__ __launch_bounds__(256) void agg1_kernel(
        const unsigned* __restrict__ hp, const float* __restrict__ as_,
        const float* __restrict__ ad_, const int* __restrict__ row_ptr,
        const int* __restrict__ col, const float* __restrict__ bias,
        float* __restrict__ out, int n) {
    int wid = (blockIdx.x * 256 + threadIdx.x) >> 6;
    int lane = threadIdx.x & 63;
    if (wid >= n) return;
    int node = wid;
    int head = lane >> 4;               // channel 2l -> head (2l)>>5 = l>>4
    float adv = ad_[(size_t)node * 4 + head];
    float e = as_[(size_t)node * 4 + head] + adv;
    e = fmaxf(e, 0.2f * e);
    float w = __expf(e);
    float s = w;
    unsigned u = hp[(size_t)node * 64 + lane];
    float acc0 = w * bflo(u), acc1 = w * bfhi(u);
    int beg = row_ptr[node], end = row_ptr[node + 1];
    for (int cb = beg; cb < end; cb += 64) {
        int m = end - cb; if (m > 64) m = 64;
        int myc = (lane < m) ? col[cb + lane] : 0;
        for (int i0 = 0; i0 < m; i0 += 8) {
            int sidx[8]; unsigned us[8]; float av[8];
            #pragma unroll
            for (int k = 0; k < 8; ++k) sidx[k] = __shfl(myc, i0 + k);
            #pragma unroll
            for (int k = 0; k < 8; ++k) us[k] = hp[(size_t)sidx[k] * 64 + lane];
            #pragma unroll
            for (int k = 0; k < 8; ++k) av[k] = as_[(size_t)sidx[k] * 4 + head];
            #pragma unroll
            for (int k = 0; k < 8; ++k) {
                if (i0 + k >= m) break;
                float ee = av[k] + adv; ee = fmaxf(ee, 0.2f * ee);
                float ww = __expf(ee);
                s += ww;
                acc0 = fmaf(ww, bflo(us[k]), acc0);
                acc1 = fmaf(ww, bfhi(us[k]), acc1);
            }
        }
    }
    float inv = 1.0f / (s + 1e-16f);
    float2 b = *(const float2*)&bias[lane * 2];
    *(float2*)&out[(size_t)node * 128 + lane * 2] =
        make_float2(acc0 * inv + b.x, acc1 * inv + b.y);
}

// Aggregation layer2: wave per dst node; half-wave per edge (2 edges/step),
// cooperative col prefetch + 8-step (16 edges) pipeline.
__global__ __launch_bounds__(256) void agg2_kernel(
        const unsigned* __restrict__ hp, const float* __restrict__ as_,
        const float* __restrict__ ad_, const int* __restrict__ row_ptr,
        const int* __restrict__ col, const float* __restrict__ bias,
        float* __restrict__ out, int n) {
    int wid = (blockIdx.x * 256 + threadIdx.x) >> 6;
    int lane = threadIdx.x & 63;
    if (wid >= n) return;
    int node = wid;
    int half = lane >> 5, wrd = lane & 31;
    float adv = ad_[node];
    float s = 0.f, acc0 = 0.f, acc1 = 0.f;
    {
        float e = as_[node] + adv; e = fmaxf(e, 0.2f * e);
        float w = __expf(e);
        if (half == 0) {
            unsigned u = hp[(size_t)node * 32 + wrd];
            s = w; acc0 = w * bflo(u); acc1 = w * bfhi(u);
        }
    }
    int beg = row_ptr[node], end = row_ptr[node + 1];
    for (int cb = beg; cb < end; cb += 64) {
        int m = end - cb; if (m > 64) m = 64;
        int myc = (lane < m) ? col[cb + lane] : 0;
        for (int i0 = 0; i0 < m; i0 += 16) {
            int sidx[8]; unsigned us[8]; float av[8];
            #pragma unroll
            for (int k = 0; k < 8; ++k) sidx[k] = __shfl(myc, i0 + 2 * k + half);
            #pragma unroll
            for (int k = 0; k < 8; ++k) us[k] = hp[(size_t)sidx[k] * 32 + wrd];
            #pragma unroll
            for (int k = 0; k < 8; ++k) av[k] = as_[sidx[k]];
            #pragma unroll
            for (int k = 0; k < 8; ++k) {
                if (i0 + 2 * k + half < m) {
                    float ee = av[k] + adv; ee = fmaxf(ee, 0.2f * ee);
                    float ww = __expf(ee);
                    s += ww;
                    acc0 = fmaf(ww, bflo(us[k]), acc0);
                    acc1 = fmaf(ww, bfhi(us[k]), acc1);
                }
            }
        }
    }
    s += __shfl_xor(s, 32);
    acc0 += __shfl_xor(acc0, 32);
    acc1 += __shfl_xor(acc1, 32);
    if (half == 0) {
        float inv = 1.0f / (s + 1e-16f);
        float2 b = *(const float2*)&bias[wrd * 2];
        *(float2*)&out[(size_t)node * 64 + wrd * 2] =
            make_float2(acc0 * inv + b.x, acc1 * inv + b.y);
    }
}

// ---------------------------------------------------------------------------
extern "C" void kernel_launch(void* const* d_in, const int* in_sizes, int n_in,
                              void* d_out, int out_size, void* d_ws, size_t ws_size,
                              hipStream_t stream) {
    const float* inp   = (const float*)d_in[0];
    const int*   ei    = (const int*)d_in[1];
    const float* W1    = (const float*)d_in[2];
    const float* atts1 = (const float*)d_in[3];
    const float* attd1 = (const float*)d_in[4];
    const float* bias1 = (const float*)d_in[5];
    const float* W2    = (const float*)d_in[6];
    const float* atts2 = (const float*)d_in[7];
    const float* attd2 = (const float*)d_in[8];
    const float* bias2 = (const float*)d_in[9];
    float* out = (float*)d_out;

    const int N = N_NODES;
    const int E = in_sizes[1] / 2;

    unsigned* h1p = (unsigned*)d_ws;               // N*64 uints (layer2 reuses N*32)
    float* x1  = (float*)(h1p + (size_t)N * 64);   // N*128 f32
    float* as1 = x1 + (size_t)N * 128;             // N*4
    float* ad1 = as1 + (size_t)N * 4;              // N*4
    int* cnt      = (int*)(ad1 + (size_t)N * 4);   // N
    int* row_ptr  = cnt + N;                       // N+1
    int* fill_ptr = row_ptr + N + 1;               // N
    int* bsum     = fill_ptr + N;                  // 128
    int* flag     = bsum + 128;                    // 1
    int* col      = flag + 1;                      // E

    hipMemsetAsync(cnt, 0, N * sizeof(int), stream);
    detect_kernel<<<1, 64, 0, stream>>>(ei, flag);

    int nb = (N + SCAN_BLOCK - 1) / SCAN_BLOCK;
    count_kernel<<<(E + 255) / 256, 256, 0, stream>>>(ei, flag, cnt, E);
    scanA_kernel<<<nb, SCAN_BLOCK, 0, stream>>>(cnt, row_ptr, bsum, N);
    scanB_kernel<<<1, 128, 0, stream>>>(bsum, nb, row_ptr + N, E);
    scanC_kernel<<<nb, SCAN_BLOCK, 0, stream>>>(row_ptr, fill_ptr, bsum, N);
    fill_kernel<<<(E + 255) / 256, 256, 0, stream>>>(ei, flag, fill_ptr, col, E);

    // layer 1
    gemm1_kernel<<<(N + 31) / 32, 256, 0, stream>>>(inp, W1, atts1, attd1, h1p, as1, ad1, N);
    agg1_kernel<<<(N + 3) / 4, 256, 0, stream>>>(h1p, as1, ad1, row_ptr, col, bias1, x1, N);

    // layer 2 (h2p aliases h1p; as2/ad2 alias as1/ad1)
    gemm2_kernel<<<(N + 63) / 64, 256, 0, stream>>>(x1, W2, atts2, attd2, h1p, as1, ad1, N);
    agg2_kernel<<<(N + 3) / 4, 256, 0, stream>>>(h1p, as1, ad1, row_ptr, col, bias2, out, N);
}

// Round 4
// 380.029 us; speedup vs baseline: 2.0450x; 1.2314x over previous
//
#include <hip/hip_runtime.h>

#define N_NODES 100000
#define F1 128
#define NCLS 64
#define EPB 8   // edges per thread in CSR-build kernels

__device__ __forceinline__ unsigned f2bf(float x) {
    unsigned u = __builtin_bit_cast(unsigned, x);
    u += 0x7fff + ((u >> 16) & 1);
    return u >> 16;
}
__device__ __forceinline__ float bflo(unsigned u) {
    return __builtin_bit_cast(float, u << 16);
}
__device__ __forceinline__ float bfhi(unsigned u) {
    return __builtin_bit_cast(float, u & 0xffff0000u);
}

// ---------------------------------------------------------------------------
// Edge dtype probe (int64 vs int32 edge_index)
__global__ void detect_kernel(const int* __restrict__ ei, int* __restrict__ flag) {
    int tid = threadIdx.x;
    int v = ei[2 * tid + 1];
    unsigned long long ball = __ballot(v == 0);
    if (tid == 0) *flag = (ball == ~0ull) ? 1 : 0;
}

__device__ __forceinline__ int load_edge(const int* ei, int is64, long long idx) {
    return is64 ? ei[2 * idx] : ei[idx];
}

// ---------------------------------------------------------------------------
// CSR build: count(+rank) -> scan -> fill(no atomic)
__global__ void count_kernel(const int* __restrict__ ei, const int* __restrict__ flag,
                             int* __restrict__ cnt, int* __restrict__ rank, int E) {
    long long base = (long long)(blockIdx.x * blockDim.x + threadIdx.x) * EPB;
    if (base >= E) return;
    int is64 = *flag;
    int d[EPB];
    #pragma unroll
    for (int k = 0; k < EPB; ++k) {
        long long e = base + k;
        d[k] = (e < E) ? load_edge(ei, is64, (long long)E + e) : -1;
    }
    int r[EPB];
    #pragma unroll
    for (int k = 0; k < EPB; ++k)
        if (d[k] >= 0) r[k] = atomicAdd(&cnt[d[k]], 1);
    #pragma unroll
    for (int k = 0; k < EPB; ++k)
        if (d[k] >= 0) rank[base + k] = r[k];
}

#define SCAN_BLOCK 1024
__global__ void scanA_kernel(const int* __restrict__ cnt, int* __restrict__ excl,
                             int* __restrict__ bsum, int n) {
    __shared__ int sm[SCAN_BLOCK];
    int tid = threadIdx.x;
    int i = blockIdx.x * SCAN_BLOCK + tid;
    int v = (i < n) ? cnt[i] : 0;
    sm[tid] = v;
    __syncthreads();
    for (int off = 1; off < SCAN_BLOCK; off <<= 1) {
        int t = (tid >= off) ? sm[tid - off] : 0;
        __syncthreads();
        sm[tid] += t;
        __syncthreads();
    }
    if (i < n) excl[i] = sm[tid] - v;
    if (tid == SCAN_BLOCK - 1) bsum[blockIdx.x] = sm[tid];
}

__global__ void scanB_kernel(int* __restrict__ bsum, int nb,
                             int* __restrict__ row_last, int total) {
    __shared__ int sm[128];
    int tid = threadIdx.x;
    int v = (tid < nb) ? bsum[tid] : 0;
    sm[tid] = v;
    __syncthreads();
    for (int off = 1; off < 128; off <<= 1) {
        int t = (tid >= off) ? sm[tid - off] : 0;
        __syncthreads();
        sm[tid] += t;
        __syncthreads();
    }
    if (tid < nb) bsum[tid] = sm[tid] - v;
    if (tid == 0) *row_last = total;
}

__global__ void scanC_kernel(int* __restrict__ row_ptr, const int* __restrict__ bsum, int n) {
    int i = blockIdx.x * SCAN_BLOCK + threadIdx.x;
    if (i < n) row_ptr[i] += bsum[blockIdx.x];
}

__global__ void fill_kernel(const int* __restrict__ ei, const int* __restrict__ flag,
                            const int* __restrict__ row_ptr, const int* __restrict__ rank,
                            int* __restrict__ col, int E) {
    long long base = (long long)(blockIdx.x * blockDim.x + threadIdx.x) * EPB;
    if (base >= E) return;
    int is64 = *flag;
    int d[EPB], s[EPB], r[EPB], rp[EPB];
    #pragma unroll
    for (int k = 0; k < EPB; ++k) {
        long long e = base + k;
        d[k] = (e < E) ? load_edge(ei, is64, (long long)E + e) : -1;
    }
    #pragma unroll
    for (int k = 0; k < EPB; ++k) {
        long long e = base + k;
        s[k] = (e < E) ? load_edge(ei, is64, e) : 0;
    }
    #pragma unroll
    for (int k = 0; k < EPB; ++k)
        if (d[k] >= 0) { r[k] = rank[base + k]; }
    #pragma unroll
    for (int k = 0; k < EPB; ++k)
        if (d[k] >= 0) rp[k] = row_ptr[d[k]];
    #pragma unroll
    for (int k = 0; k < EPB; ++k)
        if (d[k] >= 0) col[rp[k] + r[k]] = s[k];
}

// ---------------------------------------------------------------------------
// Layer1 GEMM: [N,128]x[128,128], 2D register tile 4 nodes x 4 channels/thread.
__global__ __launch_bounds__(256) void gemm1_kernel(
        const float* __restrict__ x, const float* __restrict__ W,
        const float* __restrict__ att_s, const float* __restrict__ att_d,
        unsigned* __restrict__ hp, float* __restrict__ as_, float* __restrict__ ad_, int n) {
    __shared__ float xs[32][128];   // 16 KB
    __shared__ float Ws[32][128];   // 16 KB (K-chunk)
    int tid = threadIdx.x;
    int cg = tid & 31, ng = tid >> 5;
    int c0 = cg * 4;
    int base = blockIdx.x * 32;
    for (int i = tid; i < 1024; i += 256) {
        int r = i >> 5, o = (i & 31) * 4;
        float4 v = make_float4(0.f, 0.f, 0.f, 0.f);
        if (base + r < n) v = *(const float4*)&x[(size_t)(base + r) * 128 + o];
        *(float4*)&xs[r][o] = v;
    }
    float acc[4][4] = {};
    for (int fc = 0; fc < 4; ++fc) {
        __syncthreads();
        for (int i = tid; i < 1024; i += 256)
            *(float4*)&Ws[i >> 5][(i & 31) * 4] = *(const float4*)&W[fc * 4096 + i * 4];
        __syncthreads();
        #pragma unroll
        for (int f4 = 0; f4 < 8; ++f4) {
            float4 wf[4], xf[4];
            #pragma unroll
            for (int k = 0; k < 4; ++k) wf[k] = *(float4*)&Ws[f4 * 4 + k][c0];
            #pragma unroll
            for (int j = 0; j < 4; ++j) xf[j] = *(float4*)&xs[ng * 4 + j][fc * 32 + f4 * 4];
            #pragma unroll
            for (int k = 0; k < 4; ++k) {
                #pragma unroll
                for (int j = 0; j < 4; ++j) {
                    float xv = (&xf[j].x)[k];
                    acc[j][0] = fmaf(xv, wf[k].x, acc[j][0]);
                    acc[j][1] = fmaf(xv, wf[k].y, acc[j][1]);
                    acc[j][2] = fmaf(xv, wf[k].z, acc[j][2]);
                    acc[j][3] = fmaf(xv, wf[k].w, acc[j][3]);
                }
            }
        }
    }
    float4 asv = *(const float4*)&att_s[c0];
    float4 adv = *(const float4*)&att_d[c0];
    #pragma unroll
    for (int j = 0; j < 4; ++j) {
        int node = base + ng * 4 + j;
        float ps = acc[j][0] * asv.x + acc[j][1] * asv.y + acc[j][2] * asv.z + acc[j][3] * asv.w;
        float pd = acc[j][0] * adv.x + acc[j][1] * adv.y + acc[j][2] * adv.z + acc[j][3] * adv.w;
        ps += __shfl_xor(ps, 1); ps += __shfl_xor(ps, 2); ps += __shfl_xor(ps, 4);
        pd += __shfl_xor(pd, 1); pd += __shfl_xor(pd, 2); pd += __shfl_xor(pd, 4);
        if (node < n) {
            uint2 pk;
            pk.x = f2bf(acc[j][0]) | (f2bf(acc[j][1]) << 16);
            pk.y = f2bf(acc[j][2]) | (f2bf(acc[j][3]) << 16);
            *(uint2*)&hp[(size_t)node * 64 + cg * 2] = pk;
            if ((cg & 7) == 0) {
                as_[(size_t)node * 4 + (cg >> 3)] = ps;
                ad_[(size_t)node * 4 + (cg >> 3)] = pd;
            }
        }
    }
}

// Layer2 GEMM: [N,128]x[128,64]
__global__ __launch_bounds__(256) void gemm2_kernel(
        const float* __restrict__ x, const float* __restrict__ W,
        const float* __restrict__ att_s, const float* __restrict__ att_d,
        unsigned* __restrict__ hp, float* __restrict__ as_, float* __restrict__ ad_, int n) {
    __shared__ float xs[64][128];   // 32 KB
    __shared__ float Ws[32][64];    // 8 KB
    int tid = threadIdx.x;
    int cg = tid & 15, ng = tid >> 4;
    int c0 = cg * 4;
    int base = blockIdx.x * 64;
    for (int i = tid; i < 2048; i += 256) {
        int r = i >> 5, o = (i & 31) * 4;
        float4 v = make_float4(0.f, 0.f, 0.f, 0.f);
        if (base + r < n) v = *(const float4*)&x[(size_t)(base + r) * 128 + o];
        *(float4*)&xs[r][o] = v;
    }
    float acc[4][4] = {};
    for (int fc = 0; fc < 4; ++fc) {
        __syncthreads();
        for (int i = tid; i < 512; i += 256)
            *(float4*)&Ws[i >> 4][(i & 15) * 4] = *(const float4*)&W[fc * 2048 + i * 4];
        __syncthreads();
        #pragma unroll
        for (int f4 = 0; f4 < 8; ++f4) {
            float4 wf[4], xf[4];
            #pragma unroll
            for (int k = 0; k < 4; ++k) wf[k] = *(float4*)&Ws[f4 * 4 + k][c0];
            #pragma unroll
            for (int j = 0; j < 4; ++j) xf[j] = *(float4*)&xs[ng * 4 + j][fc * 32 + f4 * 4];
            #pragma unroll
            for (int k = 0; k < 4; ++k) {
                #pragma unroll
                for (int j = 0; j < 4; ++j) {
                    float xv = (&xf[j].x)[k];
                    acc[j][0] = fmaf(xv, wf[k].x, acc[j][0]);
                    acc[j][1] = fmaf(xv, wf[k].y, acc[j][1]);
                    acc[j][2] = fmaf(xv, wf[k].z, acc[j][2]);
                    acc[j][3] = fmaf(xv, wf[k].w, acc[j][3]);
                }
            }
        }
    }
    float4 asv = *(const float4*)&att_s[c0];
    float4 adv = *(const float4*)&att_d[c0];
    #pragma unroll
    for (int j = 0; j < 4; ++j) {
        int node = base + ng * 4 + j;
        float ps = acc[j][0] * asv.x + acc[j][1] * asv.y + acc[j][2] * asv.z + acc[j][3] * asv.w;
        float pd = acc[j][0] * adv.x + acc[j][1] * adv.y + acc[j][2] * adv.z + acc[j][3] * adv.w;
        ps += __shfl_xor(ps, 1); ps += __shfl_xor(ps, 2);
        ps += __shfl_xor(ps, 4); ps += __shfl_xor(ps, 8);
        pd += __shfl_xor(pd, 1); pd += __shfl_xor(pd, 2);
        pd += __shfl_xor(pd, 4); pd += __shfl_xor(pd, 8);
        if (node < n) {
            uint2 pk;
            pk.x = f2bf(acc[j][0]) | (f2bf(acc[j][1]) << 16);
            pk.y = f2bf(acc[j][2]) | (f2bf(acc[j][3]) << 16);
            *(uint2*)&hp[(size_t)node * 32 + cg * 2] = pk;
            if (cg == 0) { as_[node] = ps; ad_[node] = pd; }
        }
    }
}

// ---------------------------------------------------------------------------
// Aggregation layer1: wave per dst node, lane owns channels (2l, 2l+1).
__global__ __launch_bounds__(256) void agg1_kernel(
        const unsigned* __restrict__ hp, const float* __restrict__ as_,
        const float* __restrict__ ad_, const int* __restrict__ row_ptr,
        const int* __restrict__ col, const float* __restrict__ bias,
        float* __restrict__ out, int n) {
    int wid = (blockIdx.x * 256 + threadIdx.x) >> 6;
    int lane = threadIdx.x & 63;
    if (wid >= n) return;
    int node = wid;
    int head = lane >> 4;
    float adv = ad_[(size_t)node * 4 + head];
    float e = as_[(size_t)node * 4 + head] + adv;
    e = fmaxf(e, 0.2f * e);
    float w = __expf(e);
    float s = w;
    unsigned u = hp[(size_t)node * 64 + lane];
    float acc0 = w * bflo(u), acc1 = w * bfhi(u);
    int beg = row_ptr[node], end = row_ptr[node + 1];
    for (int cb = beg; cb < end; cb += 64) {
        int m = end - cb; if (m > 64) m = 64;
        int myc = (lane < m) ? col[cb + lane] : 0;
        for (int i0 = 0; i0 < m; i0 += 8) {
            int sidx[8]; unsigned us[8]; float av[8];
            #pragma unroll
            for (int k = 0; k < 8; ++k) sidx[k] = __shfl(myc, i0 + k);
            #pragma unroll
            for (int k = 0; k < 8; ++k) us[k] = hp[(size_t)sidx[k] * 64 + lane];
            #pragma unroll
            for (int k = 0; k < 8; ++k) av[k] = as_[(size_t)sidx[k] * 4 + head];
            #pragma unroll
            for (int k = 0; k < 8; ++k) {
                if (i0 + k >= m) break;
                float ee = av[k] + adv; ee = fmaxf(ee, 0.2f * ee);
                float ww = __expf(ee);
                s += ww;
                acc0 = fmaf(ww, bflo(us[k]), acc0);
                acc1 = fmaf(ww, bfhi(us[k]), acc1);
            }
        }
    }
    float inv = 1.0f / (s + 1e-16f);
    float2 b = *(const float2*)&bias[lane * 2];
    *(float2*)&out[(size_t)node * 128 + lane * 2] =
        make_float2(acc0 * inv + b.x, acc1 * inv + b.y);
}

// Aggregation layer2: wave per dst node; half-wave per edge (2 edges/step).
__global__ __launch_bounds__(256) void agg2_kernel(
        const unsigned* __restrict__ hp, const float* __restrict__ as_,
        const float* __restrict__ ad_, const int* __restrict__ row_ptr,
        const int* __restrict__ col, const float* __restrict__ bias,
        float* __restrict__ out, int n) {
    int wid = (blockIdx.x * 256 + threadIdx.x) >> 6;
    int lane = threadIdx.x & 63;
    if (wid >= n) return;
    int node = wid;
    int half = lane >> 5, wrd = lane & 31;
    float adv = ad_[node];
    float s = 0.f, acc0 = 0.f, acc1 = 0.f;
    {
        float e = as_[node] + adv; e = fmaxf(e, 0.2f * e);
        float w = __expf(e);
        if (half == 0) {
            unsigned u = hp[(size_t)node * 32 + wrd];
            s = w; acc0 = w * bflo(u); acc1 = w * bfhi(u);
        }
    }
    int beg = row_ptr[node], end = row_ptr[node + 1];
    for (int cb = beg; cb < end; cb += 64) {
        int m = end - cb; if (m > 64) m = 64;
        int myc = (lane < m) ? col[cb + lane] : 0;
        for (int i0 = 0; i0 < m; i0 += 16) {
            int sidx[8]; unsigned us[8]; float av[8];
            #pragma unroll
            for (int k = 0; k < 8; ++k) sidx[k] = __shfl(myc, i0 + 2 * k + half);
            #pragma unroll
            for (int k = 0; k < 8; ++k) us[k] = hp[(size_t)sidx[k] * 32 + wrd];
            #pragma unroll
            for (int k = 0; k < 8; ++k) av[k] = as_[sidx[k]];
            #pragma unroll
            for (int k = 0; k < 8; ++k) {
                if (i0 + 2 * k + half < m) {
                    float ee = av[k] + adv; ee = fmaxf(ee, 0.2f * ee);
                    float ww = __expf(ee);
                    s += ww;
                    acc0 = fmaf(ww, bflo(us[k]), acc0);
                    acc1 = fmaf(ww, bfhi(us[k]), acc1);
                }
            }
        }
    }
    s += __shfl_xor(s, 32);
    acc0 += __shfl_xor(acc0, 32);
    acc1 += __shfl_xor(acc1, 32);
    if (half == 0) {
        float inv = 1.0f / (s + 1e-16f);
        float2 b = *(const float2*)&bias[wrd * 2];
        *(float2*)&out[(size_t)node * 64 + wrd * 2] =
            make_float2(acc0 * inv + b.x, acc1 * inv + b.y);
    }
}

// ---------------------------------------------------------------------------
extern "C" void kernel_launch(void* const* d_in, const int* in_sizes, int n_in,
                              void* d_out, int out_size, void* d_ws, size_t ws_size,
                              hipStream_t stream) {
    const float* inp   = (const float*)d_in[0];
    const int*   ei    = (const int*)d_in[1];
    const float* W1    = (const float*)d_in[2];
    const float* atts1 = (const float*)d_in[3];
    const float* attd1 = (const float*)d_in[4];
    const float* bias1 = (const float*)d_in[5];
    const float* W2    = (const float*)d_in[6];
    const float* atts2 = (const float*)d_in[7];
    const float* attd2 = (const float*)d_in[8];
    const float* bias2 = (const float*)d_in[9];
    float* out = (float*)d_out;

    const int N = N_NODES;
    const int E = in_sizes[1] / 2;

    unsigned* h1p = (unsigned*)d_ws;               // N*64 uints (layer2 reuses N*32)
    float* x1  = (float*)(h1p + (size_t)N * 64);   // N*128 f32
    float* as1 = x1 + (size_t)N * 128;             // N*4
    float* ad1 = as1 + (size_t)N * 4;              // N*4
    int* cnt      = (int*)(ad1 + (size_t)N * 4);   // N
    int* row_ptr  = cnt + N;                       // N+1
    int* bsum     = row_ptr + N + 1;               // 128
    int* flag     = bsum + 128;                    // 1
    int* col      = flag + 1;                      // E
    int* rank     = (int*)x1;                      // E ints, aliases x1 (dead before agg1)

    hipMemsetAsync(cnt, 0, N * sizeof(int), stream);
    detect_kernel<<<1, 64, 0, stream>>>(ei, flag);

    int nb = (N + SCAN_BLOCK - 1) / SCAN_BLOCK;
    int ethreads = (E + EPB - 1) / EPB;
    count_kernel<<<(ethreads + 255) / 256, 256, 0, stream>>>(ei, flag, cnt, rank, E);
    scanA_kernel<<<nb, SCAN_BLOCK, 0, stream>>>(cnt, row_ptr, bsum, N);
    scanB_kernel<<<1, 128, 0, stream>>>(bsum, nb, row_ptr + N, E);
    scanC_kernel<<<nb, SCAN_BLOCK, 0, stream>>>(row_ptr, bsum, N);
    fill_kernel<<<(ethreads + 255) / 256, 256, 0, stream>>>(ei, flag, row_ptr, rank, col, E);

    // layer 1
    gemm1_kernel<<<(N + 31) / 32, 256, 0, stream>>>(inp, W1, atts1, attd1, h1p, as1, ad1, N);
    agg1_kernel<<<(N + 3) / 4, 256, 0, stream>>>(h1p, as1, ad1, row_ptr, col, bias1, x1, N);

    // layer 2 (h2p aliases h1p; as2/ad2 alias as1/ad1)
    gemm2_kernel<<<(N + 63) / 64, 256, 0, stream>>>(x1, W2, atts2, attd2, h1p, as1, ad1, N);
    agg2_kernel<<<(N + 3) / 4, 256, 0, stream>>>(h1p, as1, ad1, row_ptr, col, bias2, out, N);
}

// Round 5
// 354.967 us; speedup vs baseline: 2.1894x; 1.0706x over previous
//
#include <hip/hip_runtime.h>

#define N_NODES 100000
#define F1 128
#define NCLS 64
#define EPB 8   // edges per thread in CSR-build kernels

__device__ __forceinline__ unsigned f2bf(float x) {
    unsigned u = __builtin_bit_cast(unsigned, x);
    u += 0x7fff + ((u >> 16) & 1);
    return u >> 16;
}
__device__ __forceinline__ float bflo(unsigned u) {
    return __builtin_bit_cast(float, u << 16);
}
__device__ __forceinline__ float bfhi(unsigned u) {
    return __builtin_bit_cast(float, u & 0xffff0000u);
}

// ---------------------------------------------------------------------------
// Edge dtype probe (int64 vs int32 edge_index)
__global__ void detect_kernel(const int* __restrict__ ei, int* __restrict__ flag) {
    int tid = threadIdx.x;
    int v = ei[2 * tid + 1];
    unsigned long long ball = __ballot(v == 0);
    if (tid == 0) *flag = (ball == ~0ull) ? 1 : 0;
}

__device__ __forceinline__ int load_edge(const int* ei, int is64, long long idx) {
    return is64 ? ei[2 * idx] : ei[idx];
}

// ---------------------------------------------------------------------------
// CSR build: count(+rank) -> scan -> fill(no atomic)
__global__ void count_kernel(const int* __restrict__ ei, const int* __restrict__ flag,
                             int* __restrict__ cnt, int* __restrict__ rank, int E) {
    long long base = (long long)(blockIdx.x * blockDim.x + threadIdx.x) * EPB;
    if (base >= E) return;
    int is64 = *flag;
    int d[EPB];
    #pragma unroll
    for (int k = 0; k < EPB; ++k) {
        long long e = base + k;
        d[k] = (e < E) ? load_edge(ei, is64, (long long)E + e) : -1;
    }
    int r[EPB];
    #pragma unroll
    for (int k = 0; k < EPB; ++k)
        if (d[k] >= 0) r[k] = atomicAdd(&cnt[d[k]], 1);
    #pragma unroll
    for (int k = 0; k < EPB; ++k)
        if (d[k] >= 0) rank[base + k] = r[k];
}

#define SCAN_BLOCK 1024
__global__ void scanA_kernel(const int* __restrict__ cnt, int* __restrict__ excl,
                             int* __restrict__ bsum, int n) {
    __shared__ int sm[SCAN_BLOCK];
    int tid = threadIdx.x;
    int i = blockIdx.x * SCAN_BLOCK + tid;
    int v = (i < n) ? cnt[i] : 0;
    sm[tid] = v;
    __syncthreads();
    for (int off = 1; off < SCAN_BLOCK; off <<= 1) {
        int t = (tid >= off) ? sm[tid - off] : 0;
        __syncthreads();
        sm[tid] += t;
        __syncthreads();
    }
    if (i < n) excl[i] = sm[tid] - v;
    if (tid == SCAN_BLOCK - 1) bsum[blockIdx.x] = sm[tid];
}

__global__ void scanB_kernel(int* __restrict__ bsum, int nb,
                             int* __restrict__ row_last, int total) {
    __shared__ int sm[128];
    int tid = threadIdx.x;
    int v = (tid < nb) ? bsum[tid] : 0;
    sm[tid] = v;
    __syncthreads();
    for (int off = 1; off < 128; off <<= 1) {
        int t = (tid >= off) ? sm[tid - off] : 0;
        __syncthreads();
        sm[tid] += t;
        __syncthreads();
    }
    if (tid < nb) bsum[tid] = sm[tid] - v;
    if (tid == 0) *row_last = total;
}

__global__ void scanC_kernel(int* __restrict__ row_ptr, const int* __restrict__ bsum, int n) {
    int i = blockIdx.x * SCAN_BLOCK + threadIdx.x;
    if (i < n) row_ptr[i] += bsum[blockIdx.x];
}

__global__ void fill_kernel(const int* __restrict__ ei, const int* __restrict__ flag,
                            const int* __restrict__ row_ptr, const int* __restrict__ rank,
                            int* __restrict__ col, int E) {
    long long base = (long long)(blockIdx.x * blockDim.x + threadIdx.x) * EPB;
    if (base >= E) return;
    int is64 = *flag;
    int d[EPB], s[EPB], r[EPB], rp[EPB];
    #pragma unroll
    for (int k = 0; k < EPB; ++k) {
        long long e = base + k;
        d[k] = (e < E) ? load_edge(ei, is64, (long long)E + e) : -1;
    }
    #pragma unroll
    for (int k = 0; k < EPB; ++k) {
        long long e = base + k;
        s[k] = (e < E) ? load_edge(ei, is64, e) : 0;
    }
    #pragma unroll
    for (int k = 0; k < EPB; ++k)
        if (d[k] >= 0) { r[k] = rank[base + k]; }
    #pragma unroll
    for (int k = 0; k < EPB; ++k)
        if (d[k] >= 0) rp[k] = row_ptr[d[k]];
    #pragma unroll
    for (int k = 0; k < EPB; ++k)
        if (d[k] >= 0) col[rp[k] + r[k]] = s[k];
}

// ---------------------------------------------------------------------------
// Layer1 GEMM: [N,128]x[128,128], 64-node tile, 8 nodes x 4 channels/thread.
__global__ __launch_bounds__(256) void gemm1_kernel(
        const float* __restrict__ x, const float* __restrict__ W,
        const float* __restrict__ att_s, const float* __restrict__ att_d,
        unsigned* __restrict__ hp, float* __restrict__ as_, float* __restrict__ ad_, int n) {
    __shared__ float xs[64][128];   // 32 KB
    __shared__ float Ws[32][128];   // 16 KB (K-chunk)
    int tid = threadIdx.x;
    int cg = tid & 31, ng = tid >> 5;   // ng 0..7 -> nodes ng*8..ng*8+7
    int c0 = cg * 4;
    int base = blockIdx.x * 64;
    for (int i = tid; i < 2048; i += 256) {
        int r = i >> 5, o = (i & 31) * 4;
        float4 v = make_float4(0.f, 0.f, 0.f, 0.f);
        if (base + r < n) v = *(const float4*)&x[(size_t)(base + r) * 128 + o];
        *(float4*)&xs[r][o] = v;
    }
    float acc[8][4] = {};
    for (int fc = 0; fc < 4; ++fc) {
        __syncthreads();
        for (int i = tid; i < 1024; i += 256)
            *(float4*)&Ws[i >> 5][(i & 31) * 4] = *(const float4*)&W[fc * 4096 + i * 4];
        __syncthreads();
        #pragma unroll
        for (int f4 = 0; f4 < 8; ++f4) {
            float4 wf[4], xf[8];
            #pragma unroll
            for (int k = 0; k < 4; ++k) wf[k] = *(float4*)&Ws[f4 * 4 + k][c0];
            #pragma unroll
            for (int j = 0; j < 8; ++j) xf[j] = *(float4*)&xs[ng * 8 + j][fc * 32 + f4 * 4];
            #pragma unroll
            for (int k = 0; k < 4; ++k) {
                #pragma unroll
                for (int j = 0; j < 8; ++j) {
                    float xv = (&xf[j].x)[k];
                    acc[j][0] = fmaf(xv, wf[k].x, acc[j][0]);
                    acc[j][1] = fmaf(xv, wf[k].y, acc[j][1]);
                    acc[j][2] = fmaf(xv, wf[k].z, acc[j][2]);
                    acc[j][3] = fmaf(xv, wf[k].w, acc[j][3]);
                }
            }
        }
    }
    float4 asv = *(const float4*)&att_s[c0];
    float4 adv = *(const float4*)&att_d[c0];
    #pragma unroll
    for (int j = 0; j < 8; ++j) {
        int node = base + ng * 8 + j;
        float ps = acc[j][0] * asv.x + acc[j][1] * asv.y + acc[j][2] * asv.z + acc[j][3] * asv.w;
        float pd = acc[j][0] * adv.x + acc[j][1] * adv.y + acc[j][2] * adv.z + acc[j][3] * adv.w;
        ps += __shfl_xor(ps, 1); ps += __shfl_xor(ps, 2); ps += __shfl_xor(ps, 4);
        pd += __shfl_xor(pd, 1); pd += __shfl_xor(pd, 2); pd += __shfl_xor(pd, 4);
        if (node < n) {
            uint2 pk;
            pk.x = f2bf(acc[j][0]) | (f2bf(acc[j][1]) << 16);
            pk.y = f2bf(acc[j][2]) | (f2bf(acc[j][3]) << 16);
            *(uint2*)&hp[(size_t)node * 64 + cg * 2] = pk;
            if ((cg & 7) == 0) {
                as_[(size_t)node * 4 + (cg >> 3)] = ps;
                ad_[(size_t)node * 4 + (cg >> 3)] = pd;
            }
        }
    }
}

// Layer2 GEMM: [N,128(bf16-packed)]x[128,64], 64-node tile, 4x4 reg tile.
__global__ __launch_bounds__(256) void gemm2_kernel(
        const unsigned* __restrict__ xp, const float* __restrict__ W,
        const float* __restrict__ att_s, const float* __restrict__ att_d,
        unsigned* __restrict__ hp, float* __restrict__ as_, float* __restrict__ ad_, int n) {
    __shared__ float xs[64][128];   // 32 KB
    __shared__ float Ws[32][64];    // 8 KB
    int tid = threadIdx.x;
    int cg = tid & 15, ng = tid >> 4;
    int c0 = cg * 4;
    int base = blockIdx.x * 64;
    for (int i = tid; i < 1024; i += 256) {       // 64 rows x 16 uint4
        int r = i >> 4, o = (i & 15) * 4;
        uint4 u = make_uint4(0, 0, 0, 0);
        if (base + r < n) u = *(const uint4*)&xp[(size_t)(base + r) * 64 + o];
        float* dst = &xs[r][o * 2];
        dst[0] = bflo(u.x); dst[1] = bfhi(u.x);
        dst[2] = bflo(u.y); dst[3] = bfhi(u.y);
        dst[4] = bflo(u.z); dst[5] = bfhi(u.z);
        dst[6] = bflo(u.w); dst[7] = bfhi(u.w);
    }
    float acc[4][4] = {};
    for (int fc = 0; fc < 4; ++fc) {
        __syncthreads();
        for (int i = tid; i < 512; i += 256)
            *(float4*)&Ws[i >> 4][(i & 15) * 4] = *(const float4*)&W[fc * 2048 + i * 4];
        __syncthreads();
        #pragma unroll
        for (int f4 = 0; f4 < 8; ++f4) {
            float4 wf[4], xf[4];
            #pragma unroll
            for (int k = 0; k < 4; ++k) wf[k] = *(float4*)&Ws[f4 * 4 + k][c0];
            #pragma unroll
            for (int j = 0; j < 4; ++j) xf[j] = *(float4*)&xs[ng * 4 + j][fc * 32 + f4 * 4];
            #pragma unroll
            for (int k = 0; k < 4; ++k) {
                #pragma unroll
                for (int j = 0; j < 4; ++j) {
                    float xv = (&xf[j].x)[k];
                    acc[j][0] = fmaf(xv, wf[k].x, acc[j][0]);
                    acc[j][1] = fmaf(xv, wf[k].y, acc[j][1]);
                    acc[j][2] = fmaf(xv, wf[k].z, acc[j][2]);
                    acc[j][3] = fmaf(xv, wf[k].w, acc[j][3]);
                }
            }
        }
    }
    float4 asv = *(const float4*)&att_s[c0];
    float4 adv = *(const float4*)&att_d[c0];
    #pragma unroll
    for (int j = 0; j < 4; ++j) {
        int node = base + ng * 4 + j;
        float ps = acc[j][0] * asv.x + acc[j][1] * asv.y + acc[j][2] * asv.z + acc[j][3] * asv.w;
        float pd = acc[j][0] * adv.x + acc[j][1] * adv.y + acc[j][2] * adv.z + acc[j][3] * adv.w;
        ps += __shfl_xor(ps, 1); ps += __shfl_xor(ps, 2);
        ps += __shfl_xor(ps, 4); ps += __shfl_xor(ps, 8);
        pd += __shfl_xor(pd, 1); pd += __shfl_xor(pd, 2);
        pd += __shfl_xor(pd, 4); pd += __shfl_xor(pd, 8);
        if (node < n) {
            uint2 pk;
            pk.x = f2bf(acc[j][0]) | (f2bf(acc[j][1]) << 16);
            pk.y = f2bf(acc[j][2]) | (f2bf(acc[j][3]) << 16);
            *(uint2*)&hp[(size_t)node * 32 + cg * 2] = pk;
            if (cg == 0) { as_[node] = ps; ad_[node] = pd; }
        }
    }
}

// ---------------------------------------------------------------------------
// Aggregation layer1: wave per dst node, lane owns channels (2l, 2l+1).
// Lane-specialized exp (lane 4k+h computes edge k / head h weight, once per
// 16-edge batch), cooperative col load, 16-deep clamped gather pipeline.
__global__ __launch_bounds__(256) void agg1_kernel(
        const unsigned* __restrict__ hp, const float* __restrict__ as_,
        const float* __restrict__ ad_, const int* __restrict__ row_ptr,
        const int* __restrict__ col, const float* __restrict__ bias,
        unsigned* __restrict__ outp, int n) {
    int wid = (blockIdx.x * 256 + threadIdx.x) >> 6;
    int lane = threadIdx.x & 63;
    if (wid >= n) return;
    int node = wid;
    int head = lane >> 4;                   // head of channels (2l, 2l+1)
    int hspec = lane & 3;                   // specialist head
    float adv_own  = ad_[(size_t)node * 4 + head];
    float adv_spec = ad_[(size_t)node * 4 + hspec];
    // self loop
    float e0 = as_[(size_t)node * 4 + head] + adv_own;
    e0 = fmaxf(e0, 0.2f * e0);
    float w0 = __expf(e0);
    float s = w0;
    unsigned u0 = hp[(size_t)node * 64 + lane];
    float acc0 = w0 * bflo(u0), acc1 = w0 * bfhi(u0);
    int beg = row_ptr[node], end = row_ptr[node + 1];
    for (int cb = beg; cb < end; cb += 64) {
        int m = end - cb; if (m > 64) m = 64;
        int myc = (lane < m) ? col[cb + lane] : 0;
        for (int b16 = 0; b16 < m; b16 += 16) {
            // specialist: weight for (edge b16 + lane/4, head lane&3)
            int jj = b16 + (lane >> 2); jj = (jj < m) ? jj : (m - 1);
            int sspec = __shfl(myc, jj);
            float ee = as_[(size_t)sspec * 4 + hspec] + adv_spec;
            ee = fmaxf(ee, 0.2f * ee);
            float ew = __expf(ee);
            int sidx[16]; unsigned us[16];
            #pragma unroll
            for (int k = 0; k < 16; ++k) {
                int kk = b16 + k; kk = (kk < m) ? kk : (m - 1);
                sidx[k] = __shfl(myc, kk);
            }
            #pragma unroll
            for (int k = 0; k < 16; ++k) us[k] = hp[(size_t)sidx[k] * 64 + lane];
            #pragma unroll
            for (int k = 0; k < 16; ++k) {
                int kk = b16 + k; int valid = kk < m; kk = valid ? kk : (m - 1);
                float ww = __shfl(ew, ((kk - b16) << 2) | head);
                ww = valid ? ww : 0.f;
                s += ww;
                acc0 = fmaf(ww, bflo(us[k]), acc0);
                acc1 = fmaf(ww, bfhi(us[k]), acc1);
            }
        }
    }
    float inv = 1.0f / (s + 1e-16f);
    float2 b = *(const float2*)&bias[lane * 2];
    outp[(size_t)node * 64 + lane] =
        f2bf(acc0 * inv + b.x) | (f2bf(acc1 * inv + b.y) << 16);
}

// Aggregation layer2: wave per dst node; half-wave per edge (2 edges/step),
// per-lane exp once per 64-edge batch, 8-deep clamped pipeline.
__global__ __launch_bounds__(256) void agg2_kernel(
        const unsigned* __restrict__ hp, const float* __restrict__ as_,
        const float* __restrict__ ad_, const int* __restrict__ row_ptr,
        const int* __restrict__ col, const float* __restrict__ bias,
        float* __restrict__ out, int n) {
    int wid = (blockIdx.x * 256 + threadIdx.x) >> 6;
    int lane = threadIdx.x & 63;
    if (wid >= n) return;
    int node = wid;
    int half = lane >> 5, wrd = lane & 31;
    float adv = ad_[node];
    float s = 0.f, acc0 = 0.f, acc1 = 0.f;
    {
        float e = as_[node] + adv; e = fmaxf(e, 0.2f * e);
        float w = __expf(e);
        if (half == 0) {
            unsigned u = hp[(size_t)node * 32 + wrd];
            s = w; acc0 = w * bflo(u); acc1 = w * bfhi(u);
        }
    }
    int beg = row_ptr[node], end = row_ptr[node + 1];
    for (int cb = beg; cb < end; cb += 64) {
        int m = end - cb; if (m > 64) m = 64;
        int myc = (lane < m) ? col[cb + lane] : 0;
        float ee = as_[myc] + adv; ee = fmaxf(ee, 0.2f * ee);
        float ewl = __expf(ee);
        for (int i0 = 0; i0 < m; i0 += 16) {
            int sidx[8]; unsigned us[8];
            #pragma unroll
            for (int k = 0; k < 8; ++k) {
                int idx = i0 + 2 * k + half; idx = (idx < m) ? idx : (m - 1);
                sidx[k] = __shfl(myc, idx);
            }
            #pragma unroll
            for (int k = 0; k < 8; ++k) us[k] = hp[(size_t)sidx[k] * 32 + wrd];
            #pragma unroll
            for (int k = 0; k < 8; ++k) {
                int idx = i0 + 2 * k + half; int valid = idx < m;
                idx = valid ? idx : (m - 1);
                float ww = __shfl(ewl, idx);
                ww = valid ? ww : 0.f;
                s += ww;
                acc0 = fmaf(ww, bflo(us[k]), acc0);
                acc1 = fmaf(ww, bfhi(us[k]), acc1);
            }
        }
    }
    s += __shfl_xor(s, 32);
    acc0 += __shfl_xor(acc0, 32);
    acc1 += __shfl_xor(acc1, 32);
    if (half == 0) {
        float inv = 1.0f / (s + 1e-16f);
        float2 b = *(const float2*)&bias[wrd * 2];
        *(float2*)&out[(size_t)node * 64 + wrd * 2] =
            make_float2(acc0 * inv + b.x, acc1 * inv + b.y);
    }
}

// ---------------------------------------------------------------------------
extern "C" void kernel_launch(void* const* d_in, const int* in_sizes, int n_in,
                              void* d_out, int out_size, void* d_ws, size_t ws_size,
                              hipStream_t stream) {
    const float* inp   = (const float*)d_in[0];
    const int*   ei    = (const int*)d_in[1];
    const float* W1    = (const float*)d_in[2];
    const float* atts1 = (const float*)d_in[3];
    const float* attd1 = (const float*)d_in[4];
    const float* bias1 = (const float*)d_in[5];
    const float* W2    = (const float*)d_in[6];
    const float* atts2 = (const float*)d_in[7];
    const float* attd2 = (const float*)d_in[8];
    const float* bias2 = (const float*)d_in[9];
    float* out = (float*)d_out;

    const int N = N_NODES;
    const int E = in_sizes[1] / 2;

    unsigned* h1p = (unsigned*)d_ws;               // N*64 uints (layer2 reuses N*32)
    unsigned* x1p = h1p + (size_t)N * 64;          // N*64 uints (bf16-packed x1)
    float* as1 = (float*)(x1p + (size_t)N * 64);   // N*4
    float* ad1 = as1 + (size_t)N * 4;              // N*4
    int* cnt      = (int*)(ad1 + (size_t)N * 4);   // N
    int* row_ptr  = cnt + N;                       // N+1
    int* bsum     = row_ptr + N + 1;               // 128
    int* flag     = bsum + 128;                    // 1
    int* col      = flag + 1;                      // E
    int* rank     = (int*)x1p;                     // E ints, aliases x1p (dead before agg1)

    hipMemsetAsync(cnt, 0, N * sizeof(int), stream);
    detect_kernel<<<1, 64, 0, stream>>>(ei, flag);

    int nb = (N + SCAN_BLOCK - 1) / SCAN_BLOCK;
    int ethreads = (E + EPB - 1) / EPB;
    count_kernel<<<(ethreads + 255) / 256, 256, 0, stream>>>(ei, flag, cnt, rank, E);
    scanA_kernel<<<nb, SCAN_BLOCK, 0, stream>>>(cnt, row_ptr, bsum, N);
    scanB_kernel<<<1, 128, 0, stream>>>(bsum, nb, row_ptr + N, E);
    scanC_kernel<<<nb, SCAN_BLOCK, 0, stream>>>(row_ptr, bsum, N);
    fill_kernel<<<(ethreads + 255) / 256, 256, 0, stream>>>(ei, flag, row_ptr, rank, col, E);

    // layer 1
    gemm1_kernel<<<(N + 63) / 64, 256, 0, stream>>>(inp, W1, atts1, attd1, h1p, as1, ad1, N);
    agg1_kernel<<<(N + 3) / 4, 256, 0, stream>>>(h1p, as1, ad1, row_ptr, col, bias1, x1p, N);

    // layer 2 (h2p aliases h1p; as2/ad2 alias as1/ad1)
    gemm2_kernel<<<(N + 63) / 64, 256, 0, stream>>>(x1p, W2, atts2, attd2, h1p, as1, ad1, N);
    agg2_kernel<<<(N + 3) / 4, 256, 0, stream>>>(h1p, as1, ad1, row_ptr, col, bias2, out, N);
}

// Round 6
// 338.115 us; speedup vs baseline: 2.2985x; 1.0498x over previous
//
#include <hip/hip_runtime.h>

#define N_NODES 100000
#define F1 128
#define NCLS 64
#define EPB 8   // edges per thread in CSR-build kernels

__device__ __forceinline__ unsigned f2bf(float x) {
    unsigned u = __builtin_bit_cast(unsigned, x);
    u += 0x7fff + ((u >> 16) & 1);
    return u >> 16;
}
__device__ __forceinline__ float bflo(unsigned u) {
    return __builtin_bit_cast(float, u << 16);
}
__device__ __forceinline__ float bfhi(unsigned u) {
    return __builtin_bit_cast(float, u & 0xffff0000u);
}

// ds_swizzle helpers (offset: BitMode, src_rel = ((i & and) | or) ^ xor, per 32-lane half)
#define SWZ_I(v, off) __builtin_amdgcn_ds_swizzle((v), (off))
#define SWZ_F(v, off) __builtin_bit_cast(float, __builtin_amdgcn_ds_swizzle(__builtin_bit_cast(int, (v)), (off)))

// ---------------------------------------------------------------------------
// Edge dtype probe (int64 vs int32 edge_index)
__global__ void detect_kernel(const int* __restrict__ ei, int* __restrict__ flag) {
    int tid = threadIdx.x;
    int v = ei[2 * tid + 1];
    unsigned long long ball = __ballot(v == 0);
    if (tid == 0) *flag = (ball == ~0ull) ? 1 : 0;
}

__device__ __forceinline__ int load_edge(const int* ei, int is64, long long idx) {
    return is64 ? ei[2 * idx] : ei[idx];
}

// ---------------------------------------------------------------------------
// CSR build: count(+rank) -> scan -> fill(no atomic)
__global__ void count_kernel(const int* __restrict__ ei, const int* __restrict__ flag,
                             int* __restrict__ cnt, int* __restrict__ rank, int E) {
    long long base = (long long)(blockIdx.x * blockDim.x + threadIdx.x) * EPB;
    if (base >= E) return;
    int is64 = *flag;
    int d[EPB];
    #pragma unroll
    for (int k = 0; k < EPB; ++k) {
        long long e = base + k;
        d[k] = (e < E) ? load_edge(ei, is64, (long long)E + e) : -1;
    }
    int r[EPB];
    #pragma unroll
    for (int k = 0; k < EPB; ++k)
        if (d[k] >= 0) r[k] = atomicAdd(&cnt[d[k]], 1);
    #pragma unroll
    for (int k = 0; k < EPB; ++k)
        if (d[k] >= 0) rank[base + k] = r[k];
}

#define SCAN_BLOCK 1024
__global__ void scanA_kernel(const int* __restrict__ cnt, int* __restrict__ excl,
                             int* __restrict__ bsum, int n) {
    __shared__ int sm[SCAN_BLOCK];
    int tid = threadIdx.x;
    int i = blockIdx.x * SCAN_BLOCK + tid;
    int v = (i < n) ? cnt[i] : 0;
    sm[tid] = v;
    __syncthreads();
    for (int off = 1; off < SCAN_BLOCK; off <<= 1) {
        int t = (tid >= off) ? sm[tid - off] : 0;
        __syncthreads();
        sm[tid] += t;
        __syncthreads();
    }
    if (i < n) excl[i] = sm[tid] - v;
    if (tid == SCAN_BLOCK - 1) bsum[blockIdx.x] = sm[tid];
}

__global__ void scanB_kernel(int* __restrict__ bsum, int nb,
                             int* __restrict__ row_last, int total) {
    __shared__ int sm[128];
    int tid = threadIdx.x;
    int v = (tid < nb) ? bsum[tid] : 0;
    sm[tid] = v;
    __syncthreads();
    for (int off = 1; off < 128; off <<= 1) {
        int t = (tid >= off) ? sm[tid - off] : 0;
        __syncthreads();
        sm[tid] += t;
        __syncthreads();
    }
    if (tid < nb) bsum[tid] = sm[tid] - v;
    if (tid == 0) *row_last = total;
}

__global__ void scanC_kernel(int* __restrict__ row_ptr, const int* __restrict__ bsum, int n) {
    int i = blockIdx.x * SCAN_BLOCK + threadIdx.x;
    if (i < n) row_ptr[i] += bsum[blockIdx.x];
}

__global__ void fill_kernel(const int* __restrict__ ei, const int* __restrict__ flag,
                            const int* __restrict__ row_ptr, const int* __restrict__ rank,
                            int* __restrict__ col, int E) {
    long long base = (long long)(blockIdx.x * blockDim.x + threadIdx.x) * EPB;
    if (base >= E) return;
    int is64 = *flag;
    int d[EPB], s[EPB], r[EPB], rp[EPB];
    #pragma unroll
    for (int k = 0; k < EPB; ++k) {
        long long e = base + k;
        d[k] = (e < E) ? load_edge(ei, is64, (long long)E + e) : -1;
    }
    #pragma unroll
    for (int k = 0; k < EPB; ++k) {
        long long e = base + k;
        s[k] = (e < E) ? load_edge(ei, is64, e) : 0;
    }
    #pragma unroll
    for (int k = 0; k < EPB; ++k)
        if (d[k] >= 0) { r[k] = rank[base + k]; }
    #pragma unroll
    for (int k = 0; k < EPB; ++k)
        if (d[k] >= 0) rp[k] = row_ptr[d[k]];
    #pragma unroll
    for (int k = 0; k < EPB; ++k)
        if (d[k] >= 0) col[rp[k] + r[k]] = s[k];
}

// ---------------------------------------------------------------------------
// Layer1 GEMM: [N,128]x[128,128], 64-node tile, 8 nodes x 4 channels/thread.
__global__ __launch_bounds__(256) void gemm1_kernel(
        const float* __restrict__ x, const float* __restrict__ W,
        const float* __restrict__ att_s, const float* __restrict__ att_d,
        unsigned* __restrict__ hp, float* __restrict__ as_, float* __restrict__ ad_, int n) {
    __shared__ float xs[64][128];   // 32 KB
    __shared__ float Ws[32][128];   // 16 KB (K-chunk)
    int tid = threadIdx.x;
    int cg = tid & 31, ng = tid >> 5;   // ng 0..7 -> nodes ng*8..ng*8+7
    int c0 = cg * 4;
    int base = blockIdx.x * 64;
    for (int i = tid; i < 2048; i += 256) {
        int r = i >> 5, o = (i & 31) * 4;
        float4 v = make_float4(0.f, 0.f, 0.f, 0.f);
        if (base + r < n) v = *(const float4*)&x[(size_t)(base + r) * 128 + o];
        *(float4*)&xs[r][o] = v;
    }
    float acc[8][4] = {};
    for (int fc = 0; fc < 4; ++fc) {
        __syncthreads();
        for (int i = tid; i < 1024; i += 256)
            *(float4*)&Ws[i >> 5][(i & 31) * 4] = *(const float4*)&W[fc * 4096 + i * 4];
        __syncthreads();
        #pragma unroll
        for (int f4 = 0; f4 < 8; ++f4) {
            float4 wf[4], xf[8];
            #pragma unroll
            for (int k = 0; k < 4; ++k) wf[k] = *(float4*)&Ws[f4 * 4 + k][c0];
            #pragma unroll
            for (int j = 0; j < 8; ++j) xf[j] = *(float4*)&xs[ng * 8 + j][fc * 32 + f4 * 4];
            #pragma unroll
            for (int k = 0; k < 4; ++k) {
                #pragma unroll
                for (int j = 0; j < 8; ++j) {
                    float xv = (&xf[j].x)[k];
                    acc[j][0] = fmaf(xv, wf[k].x, acc[j][0]);
                    acc[j][1] = fmaf(xv, wf[k].y, acc[j][1]);
                    acc[j][2] = fmaf(xv, wf[k].z, acc[j][2]);
                    acc[j][3] = fmaf(xv, wf[k].w, acc[j][3]);
                }
            }
        }
    }
    float4 asv = *(const float4*)&att_s[c0];
    float4 adv = *(const float4*)&att_d[c0];
    #pragma unroll
    for (int j = 0; j < 8; ++j) {
        int node = base + ng * 8 + j;
        float ps = acc[j][0] * asv.x + acc[j][1] * asv.y + acc[j][2] * asv.z + acc[j][3] * asv.w;
        float pd = acc[j][0] * adv.x + acc[j][1] * adv.y + acc[j][2] * adv.z + acc[j][3] * adv.w;
        ps += __shfl_xor(ps, 1); ps += __shfl_xor(ps, 2); ps += __shfl_xor(ps, 4);
        pd += __shfl_xor(pd, 1); pd += __shfl_xor(pd, 2); pd += __shfl_xor(pd, 4);
        if (node < n) {
            uint2 pk;
            pk.x = f2bf(acc[j][0]) | (f2bf(acc[j][1]) << 16);
            pk.y = f2bf(acc[j][2]) | (f2bf(acc[j][3]) << 16);
            *(uint2*)&hp[(size_t)node * 64 + cg * 2] = pk;
            if ((cg & 7) == 0) {
                as_[(size_t)node * 4 + (cg >> 3)] = ps;
                ad_[(size_t)node * 4 + (cg >> 3)] = pd;
            }
        }
    }
}

// Layer2 GEMM: [N,128(bf16-packed)]x[128,64], 64-node tile, 4x4 reg tile.
__global__ __launch_bounds__(256) void gemm2_kernel(
        const unsigned* __restrict__ xp, const float* __restrict__ W,
        const float* __restrict__ att_s, const float* __restrict__ att_d,
        unsigned* __restrict__ hp, float* __restrict__ as_, float* __restrict__ ad_, int n) {
    __shared__ float xs[64][128];   // 32 KB
    __shared__ float Ws[32][64];    // 8 KB
    int tid = threadIdx.x;
    int cg = tid & 15, ng = tid >> 4;
    int c0 = cg * 4;
    int base = blockIdx.x * 64;
    for (int i = tid; i < 1024; i += 256) {       // 64 rows x 16 uint4
        int r = i >> 4, o = (i & 15) * 4;
        uint4 u = make_uint4(0, 0, 0, 0);
        if (base + r < n) u = *(const uint4*)&xp[(size_t)(base + r) * 64 + o];
        float* dst = &xs[r][o * 2];
        dst[0] = bflo(u.x); dst[1] = bfhi(u.x);
        dst[2] = bflo(u.y); dst[3] = bfhi(u.y);
        dst[4] = bflo(u.z); dst[5] = bfhi(u.z);
        dst[6] = bflo(u.w); dst[7] = bfhi(u.w);
    }
    float acc[4][4] = {};
    for (int fc = 0; fc < 4; ++fc) {
        __syncthreads();
        for (int i = tid; i < 512; i += 256)
            *(float4*)&Ws[i >> 4][(i & 15) * 4] = *(const float4*)&W[fc * 2048 + i * 4];
        __syncthreads();
        #pragma unroll
        for (int f4 = 0; f4 < 8; ++f4) {
            float4 wf[4], xf[4];
            #pragma unroll
            for (int k = 0; k < 4; ++k) wf[k] = *(float4*)&Ws[f4 * 4 + k][c0];
            #pragma unroll
            for (int j = 0; j < 4; ++j) xf[j] = *(float4*)&xs[ng * 4 + j][fc * 32 + f4 * 4];
            #pragma unroll
            for (int k = 0; k < 4; ++k) {
                #pragma unroll
                for (int j = 0; j < 4; ++j) {
                    float xv = (&xf[j].x)[k];
                    acc[j][0] = fmaf(xv, wf[k].x, acc[j][0]);
                    acc[j][1] = fmaf(xv, wf[k].y, acc[j][1]);
                    acc[j][2] = fmaf(xv, wf[k].z, acc[j][2]);
                    acc[j][3] = fmaf(xv, wf[k].w, acc[j][3]);
                }
            }
        }
    }
    float4 asv = *(const float4*)&att_s[c0];
    float4 adv = *(const float4*)&att_d[c0];
    #pragma unroll
    for (int j = 0; j < 4; ++j) {
        int node = base + ng * 4 + j;
        float ps = acc[j][0] * asv.x + acc[j][1] * asv.y + acc[j][2] * asv.z + acc[j][3] * asv.w;
        float pd = acc[j][0] * adv.x + acc[j][1] * adv.y + acc[j][2] * adv.z + acc[j][3] * adv.w;
        ps += __shfl_xor(ps, 1); ps += __shfl_xor(ps, 2);
        ps += __shfl_xor(ps, 4); ps += __shfl_xor(ps, 8);
        pd += __shfl_xor(pd, 1); pd += __shfl_xor(pd, 2);
        pd += __shfl_xor(pd, 4); pd += __shfl_xor(pd, 8);
        if (node < n) {
            uint2 pk;
            pk.x = f2bf(acc[j][0]) | (f2bf(acc[j][1]) << 16);
            pk.y = f2bf(acc[j][2]) | (f2bf(acc[j][3]) << 16);
            *(uint2*)&hp[(size_t)node * 32 + cg * 2] = pk;
            if (cg == 0) { as_[node] = ps; ad_[node] = pd; }
        }
    }
}

// ---------------------------------------------------------------------------
// Aggregation layer1: wave per dst node, lane owns channels (2l, 2l+1),
// head = lane>>4. 32-edge chunks mirrored into both 32-lane halves; weights
// computed once per (edge, head) in lane layout (edge&15 | head<<4) and
// broadcast via single-instruction ds_swizzle. Branch-free 8-edge groups.
#define A1_G8(B, K0) { \
    int t0 = SWZ_I(myc, (((B)+(K0)+0)<<5)); \
    int t1 = SWZ_I(myc, (((B)+(K0)+1)<<5)); \
    int t2 = SWZ_I(myc, (((B)+(K0)+2)<<5)); \
    int t3 = SWZ_I(myc, (((B)+(K0)+3)<<5)); \
    int t4 = SWZ_I(myc, (((B)+(K0)+4)<<5)); \
    int t5 = SWZ_I(myc, (((B)+(K0)+5)<<5)); \
    int t6 = SWZ_I(myc, (((B)+(K0)+6)<<5)); \
    int t7 = SWZ_I(myc, (((B)+(K0)+7)<<5)); \
    unsigned v0 = hp[(size_t)t0 * 64 + lane]; \
    unsigned v1 = hp[(size_t)t1 * 64 + lane]; \
    unsigned v2 = hp[(size_t)t2 * 64 + lane]; \
    unsigned v3 = hp[(size_t)t3 * 64 + lane]; \
    unsigned v4 = hp[(size_t)t4 * 64 + lane]; \
    unsigned v5 = hp[(size_t)t5 * 64 + lane]; \
    unsigned v6 = hp[(size_t)t6 * 64 + lane]; \
    unsigned v7 = hp[(size_t)t7 * 64 + lane]; \
    float q0 = SWZ_F(ew, ((((K0)+0)<<5)|0x10)); \
    float q1 = SWZ_F(ew, ((((K0)+1)<<5)|0x10)); \
    float q2 = SWZ_F(ew, ((((K0)+2)<<5)|0x10)); \
    float q3 = SWZ_F(ew, ((((K0)+3)<<5)|0x10)); \
    float q4 = SWZ_F(ew, ((((K0)+4)<<5)|0x10)); \
    float q5 = SWZ_F(ew, ((((K0)+5)<<5)|0x10)); \
    float q6 = SWZ_F(ew, ((((K0)+6)<<5)|0x10)); \
    float q7 = SWZ_F(ew, ((((K0)+7)<<5)|0x10)); \
    s += q0; acc0 = fmaf(q0, bflo(v0), acc0); acc1 = fmaf(q0, bfhi(v0), acc1); \
    s += q1; acc0 = fmaf(q1, bflo(v1), acc0); acc1 = fmaf(q1, bfhi(v1), acc1); \
    s += q2; acc0 = fmaf(q2, bflo(v2), acc0); acc1 = fmaf(q2, bfhi(v2), acc1); \
    s += q3; acc0 = fmaf(q3, bflo(v3), acc0); acc1 = fmaf(q3, bfhi(v3), acc1); \
    s += q4; acc0 = fmaf(q4, bflo(v4), acc0); acc1 = fmaf(q4, bfhi(v4), acc1); \
    s += q5; acc0 = fmaf(q5, bflo(v5), acc0); acc1 = fmaf(q5, bfhi(v5), acc1); \
    s += q6; acc0 = fmaf(q6, bflo(v6), acc0); acc1 = fmaf(q6, bfhi(v6), acc1); \
    s += q7; acc0 = fmaf(q7, bflo(v7), acc0); acc1 = fmaf(q7, bfhi(v7), acc1); }

// weight lane layout: lane = (edge & 15) | (head << 4); holder's head ==
// its own channel-head (lane>>4), so adv is reused.
#define A1_SUB(B) { \
    int sspec = SWZ_I(myc, (((B)<<5) | 0x0F)); \
    float ee_ = as_[(size_t)sspec * 4 + head] + adv; \
    ee_ = fmaxf(ee_, 0.2f * ee_); \
    float ew = ((cb + (B) + (lane & 15)) < end) ? __expf(ee_) : 0.f; \
    A1_G8(B, 0) \
    if (m > (B) + 8) A1_G8(B, 8) }

__global__ __launch_bounds__(256) void agg1_kernel(
        const unsigned* __restrict__ hp, const float* __restrict__ as_,
        const float* __restrict__ ad_, const int* __restrict__ row_ptr,
        const int* __restrict__ col, const float* __restrict__ bias,
        unsigned* __restrict__ outp, int n) {
    int wid = (blockIdx.x * 256 + threadIdx.x) >> 6;
    int lane = threadIdx.x & 63;
    if (wid >= n) return;
    int node = wid;
    int head = lane >> 4;                   // head of channels (2l, 2l+1)
    float adv = ad_[(size_t)node * 4 + head];
    // self loop
    float e0 = as_[(size_t)node * 4 + head] + adv;
    e0 = fmaxf(e0, 0.2f * e0);
    float w0 = __expf(e0);
    float s = w0;
    unsigned u0 = hp[(size_t)node * 64 + lane];
    float acc0 = w0 * bflo(u0), acc1 = w0 * bfhi(u0);
    int beg = row_ptr[node], end = row_ptr[node + 1];
    for (int cb = beg; cb < end; cb += 32) {
        int m = end - cb; if (m > 32) m = 32;
        int ci = cb + (lane & 31);
        int myc = col[(ci < end) ? ci : (end - 1)];   // mirrored into both halves
        A1_SUB(0)
        if (m > 16) A1_SUB(16)
    }
    float inv = 1.0f / (s + 1e-16f);
    float2 b = *(const float2*)&bias[lane * 2];
    outp[(size_t)node * 64 + lane] =
        f2bf(acc0 * inv + b.x) | (f2bf(acc1 * inv + b.y) << 16);
}

// Aggregation layer2: wave per dst node; lane owns word (lane&31) of 32;
// halves process even/odd edges (col loaded interleaved so one swizzle
// constant serves both). 1 exp per lane per 64-edge chunk.
#define A2_G4(K0) { \
    int t0 = SWZ_I(myc, (((K0)+0)<<5)); \
    int t1 = SWZ_I(myc, (((K0)+1)<<5)); \
    int t2 = SWZ_I(myc, (((K0)+2)<<5)); \
    int t3 = SWZ_I(myc, (((K0)+3)<<5)); \
    unsigned v0 = hp[(size_t)t0 * 32 + wrd]; \
    unsigned v1 = hp[(size_t)t1 * 32 + wrd]; \
    unsigned v2 = hp[(size_t)t2 * 32 + wrd]; \
    unsigned v3 = hp[(size_t)t3 * 32 + wrd]; \
    float q0 = SWZ_F(ew, (((K0)+0)<<5)); \
    float q1 = SWZ_F(ew, (((K0)+1)<<5)); \
    float q2 = SWZ_F(ew, (((K0)+2)<<5)); \
    float q3 = SWZ_F(ew, (((K0)+3)<<5)); \
    s += q0; acc0 = fmaf(q0, bflo(v0), acc0); acc1 = fmaf(q0, bfhi(v0), acc1); \
    s += q1; acc0 = fmaf(q1, bflo(v1), acc0); acc1 = fmaf(q1, bfhi(v1), acc1); \
    s += q2; acc0 = fmaf(q2, bflo(v2), acc0); acc1 = fmaf(q2, bfhi(v2), acc1); \
    s += q3; acc0 = fmaf(q3, bflo(v3), acc0); acc1 = fmaf(q3, bfhi(v3), acc1); }

__global__ __launch_bounds__(256) void agg2_kernel(
        const unsigned* __restrict__ hp, const float* __restrict__ as_,
        const float* __restrict__ ad_, const int* __restrict__ row_ptr,
        const int* __restrict__ col, const float* __restrict__ bias,
        float* __restrict__ out, int n) {
    int wid = (blockIdx.x * 256 + threadIdx.x) >> 6;
    int lane = threadIdx.x & 63;
    if (wid >= n) return;
    int node = wid;
    int half = lane >> 5, wrd = lane & 31;
    float adv = ad_[node];
    float s = 0.f, acc0 = 0.f, acc1 = 0.f;
    {
        float e = as_[node] + adv; e = fmaxf(e, 0.2f * e);
        float w = __expf(e);
        if (half == 0) {
            unsigned u = hp[(size_t)node * 32 + wrd];
            s = w; acc0 = w * bflo(u); acc1 = w * bfhi(u);
        }
    }
    int beg = row_ptr[node], end = row_ptr[node + 1];
    for (int cb = beg; cb < end; cb += 64) {
        int m = end - cb; if (m > 64) m = 64;
        int idx = cb + 2 * (lane & 31) + half;     // lower half: even edges, upper: odd
        int myc = col[(idx < end) ? idx : (end - 1)];
        float ee = as_[myc] + adv; ee = fmaxf(ee, 0.2f * ee);
        float ew = (idx < end) ? __expf(ee) : 0.f;
        A2_G4(0)
        if (m > 8)  A2_G4(4)
        if (m > 16) A2_G4(8)
        if (m > 24) A2_G4(12)
        if (m > 32) {
            A2_G4(16)
            if (m > 40) A2_G4(20)
            if (m > 48) A2_G4(24)
            if (m > 56) A2_G4(28)
        }
    }
    s += __shfl_xor(s, 32);
    acc0 += __shfl_xor(acc0, 32);
    acc1 += __shfl_xor(acc1, 32);
    if (half == 0) {
        float inv = 1.0f / (s + 1e-16f);
        float2 b = *(const float2*)&bias[wrd * 2];
        *(float2*)&out[(size_t)node * 64 + wrd * 2] =
            make_float2(acc0 * inv + b.x, acc1 * inv + b.y);
    }
}

// ---------------------------------------------------------------------------
extern "C" void kernel_launch(void* const* d_in, const int* in_sizes, int n_in,
                              void* d_out, int out_size, void* d_ws, size_t ws_size,
                              hipStream_t stream) {
    const float* inp   = (const float*)d_in[0];
    const int*   ei    = (const int*)d_in[1];
    const float* W1    = (const float*)d_in[2];
    const float* atts1 = (const float*)d_in[3];
    const float* attd1 = (const float*)d_in[4];
    const float* bias1 = (const float*)d_in[5];
    const float* W2    = (const float*)d_in[6];
    const float* atts2 = (const float*)d_in[7];
    const float* attd2 = (const float*)d_in[8];
    const float* bias2 = (const float*)d_in[9];
    float* out = (float*)d_out;

    const int N = N_NODES;
    const int E = in_sizes[1] / 2;

    unsigned* h1p = (unsigned*)d_ws;               // N*64 uints (layer2 reuses N*32)
    unsigned* x1p = h1p + (size_t)N * 64;          // N*64 uints (bf16-packed x1)
    float* as1 = (float*)(x1p + (size_t)N * 64);   // N*4
    float* ad1 = as1 + (size_t)N * 4;              // N*4
    int* cnt      = (int*)(ad1 + (size_t)N * 4);   // N
    int* row_ptr  = cnt + N;                       // N+1
    int* bsum     = row_ptr + N + 1;               // 128
    int* flag     = bsum + 128;                    // 1
    int* col      = flag + 1;                      // E
    int* rank     = (int*)x1p;                     // E ints, aliases x1p (dead before agg1)

    hipMemsetAsync(cnt, 0, N * sizeof(int), stream);
    detect_kernel<<<1, 64, 0, stream>>>(ei, flag);

    int nb = (N + SCAN_BLOCK - 1) / SCAN_BLOCK;
    int ethreads = (E + EPB - 1) / EPB;
    count_kernel<<<(ethreads + 255) / 256, 256, 0, stream>>>(ei, flag, cnt, rank, E);
    scanA_kernel<<<nb, SCAN_BLOCK, 0, stream>>>(cnt, row_ptr, bsum, N);
    scanB_kernel<<<1, 128, 0, stream>>>(bsum, nb, row_ptr + N, E);
    scanC_kernel<<<nb, SCAN_BLOCK, 0, stream>>>(row_ptr, bsum, N);
    fill_kernel<<<(ethreads + 255) / 256, 256, 0, stream>>>(ei, flag, row_ptr, rank, col, E);

    // layer 1
    gemm1_kernel<<<(N + 63) / 64, 256, 0, stream>>>(inp, W1, atts1, attd1, h1p, as1, ad1, N);
    agg1_kernel<<<(N + 3) / 4, 256, 0, stream>>>(h1p, as1, ad1, row_ptr, col, bias1, x1p, N);

    // layer 2 (h2p aliases h1p; as2/ad2 alias as1/ad1)
    gemm2_kernel<<<(N + 63) / 64, 256, 0, stream>>>(x1p, W2, atts2, attd2, h1p, as1, ad1, N);
    agg2_kernel<<<(N + 3) / 4, 256, 0, stream>>>(h1p, as1, ad1, row_ptr, col, bias2, out, N);
}

// Round 7
// 282.864 us; speedup vs baseline: 2.7475x; 1.1953x over previous
//
#include <hip/hip_runtime.h>

#define N_NODES 100000
#define F1 128
#define NCLS 64
#define EPB 8   // edges per thread in CSR-build kernels

typedef __attribute__((ext_vector_type(8))) short bf16x8;
typedef __attribute__((ext_vector_type(4))) float f32x4;

__device__ __forceinline__ unsigned f2bf(float x) {
    unsigned u = __builtin_bit_cast(unsigned, x);
    u += 0x7fff + ((u >> 16) & 1);
    return u >> 16;
}
__device__ __forceinline__ float bflo(unsigned u) {
    return __builtin_bit_cast(float, u << 16);
}
__device__ __forceinline__ float bfhi(unsigned u) {
    return __builtin_bit_cast(float, u & 0xffff0000u);
}

// ds_swizzle helpers (offset BitMode: lane i reads ((i&and)|or)^xor, per 32-lane half)
#define SWZ_I(v, off) __builtin_amdgcn_ds_swizzle((v), (off))
#define SWZ_F(v, off) __builtin_bit_cast(float, __builtin_amdgcn_ds_swizzle(__builtin_bit_cast(int, (v)), (off)))

// ---------------------------------------------------------------------------
// Edge dtype probe (int64 vs int32 edge_index)
__global__ void detect_kernel(const int* __restrict__ ei, int* __restrict__ flag) {
    int tid = threadIdx.x;
    int v = ei[2 * tid + 1];
    unsigned long long ball = __ballot(v == 0);
    if (tid == 0) *flag = (ball == ~0ull) ? 1 : 0;
}

__device__ __forceinline__ int load_edge(const int* ei, int is64, long long idx) {
    return is64 ? ei[2 * idx] : ei[idx];
}

// ---------------------------------------------------------------------------
// CSR build: count(+rank) -> scan -> fill(no atomic)
__global__ void count_kernel(const int* __restrict__ ei, const int* __restrict__ flag,
                             int* __restrict__ cnt, int* __restrict__ rank, int E) {
    long long base = (long long)(blockIdx.x * blockDim.x + threadIdx.x) * EPB;
    if (base >= E) return;
    int is64 = *flag;
    int d[EPB];
    #pragma unroll
    for (int k = 0; k < EPB; ++k) {
        long long e = base + k;
        d[k] = (e < E) ? load_edge(ei, is64, (long long)E + e) : -1;
    }
    int r[EPB];
    #pragma unroll
    for (int k = 0; k < EPB; ++k)
        if (d[k] >= 0) r[k] = atomicAdd(&cnt[d[k]], 1);
    #pragma unroll
    for (int k = 0; k < EPB; ++k)
        if (d[k] >= 0) rank[base + k] = r[k];
}

#define SCAN_BLOCK 1024
__global__ void scanA_kernel(const int* __restrict__ cnt, int* __restrict__ excl,
                             int* __restrict__ bsum, int n) {
    __shared__ int sm[SCAN_BLOCK];
    int tid = threadIdx.x;
    int i = blockIdx.x * SCAN_BLOCK + tid;
    int v = (i < n) ? cnt[i] : 0;
    sm[tid] = v;
    __syncthreads();
    for (int off = 1; off < SCAN_BLOCK; off <<= 1) {
        int t = (tid >= off) ? sm[tid - off] : 0;
        __syncthreads();
        sm[tid] += t;
        __syncthreads();
    }
    if (i < n) excl[i] = sm[tid] - v;
    if (tid == SCAN_BLOCK - 1) bsum[blockIdx.x] = sm[tid];
}

__global__ void scanB_kernel(int* __restrict__ bsum, int nb,
                             int* __restrict__ row_last, int total) {
    __shared__ int sm[128];
    int tid = threadIdx.x;
    int v = (tid < nb) ? bsum[tid] : 0;
    sm[tid] = v;
    __syncthreads();
    for (int off = 1; off < 128; off <<= 1) {
        int t = (tid >= off) ? sm[tid - off] : 0;
        __syncthreads();
        sm[tid] += t;
        __syncthreads();
    }
    if (tid < nb) bsum[tid] = sm[tid] - v;
    if (tid == 0) *row_last = total;
}

__global__ void scanC_kernel(int* __restrict__ row_ptr, const int* __restrict__ bsum, int n) {
    int i = blockIdx.x * SCAN_BLOCK + threadIdx.x;
    if (i < n) row_ptr[i] += bsum[blockIdx.x];
}

__global__ void fill_kernel(const int* __restrict__ ei, const int* __restrict__ flag,
                            const int* __restrict__ row_ptr, const int* __restrict__ rank,
                            int* __restrict__ col, int E) {
    long long base = (long long)(blockIdx.x * blockDim.x + threadIdx.x) * EPB;
    if (base >= E) return;
    int is64 = *flag;
    int d[EPB], s[EPB], r[EPB], rp[EPB];
    #pragma unroll
    for (int k = 0; k < EPB; ++k) {
        long long e = base + k;
        d[k] = (e < E) ? load_edge(ei, is64, (long long)E + e) : -1;
    }
    #pragma unroll
    for (int k = 0; k < EPB; ++k) {
        long long e = base + k;
        s[k] = (e < E) ? load_edge(ei, is64, e) : 0;
    }
    #pragma unroll
    for (int k = 0; k < EPB; ++k)
        if (d[k] >= 0) { r[k] = rank[base + k]; }
    #pragma unroll
    for (int k = 0; k < EPB; ++k)
        if (d[k] >= 0) rp[k] = row_ptr[d[k]];
    #pragma unroll
    for (int k = 0; k < EPB; ++k)
        if (d[k] >= 0) col[rp[k] + r[k]] = s[k];
}

// ---------------------------------------------------------------------------
// Layer1 GEMM via MFMA bf16: h = x @ W1, [N,128]x[128,128].
// Block = 128 nodes, 4 waves x 32 nodes. W^T staged bf16 in LDS (XOR-swizzled
// 16B granules); A-frags converted f32->bf16 on the fly from global.
// D layout (m89): col = lane&15, row = (lane>>4)*4 + reg.
__global__ __launch_bounds__(256) void gemm1_kernel(
        const float* __restrict__ x, const float* __restrict__ W,
        const float* __restrict__ att_s, const float* __restrict__ att_d,
        unsigned* __restrict__ hp, float* __restrict__ as_, float* __restrict__ ad_, int n) {
    __shared__ uint4 WtS[2048];                 // 32 KB: Wt[128ch][128k] bf16
    unsigned* Wt = (unsigned*)WtS;
    int tid = threadIdx.x;
    {   // stage W^T (convert f32->bf16), swizzle bytecol ^= (ch&7)<<4
        int ch = tid & 127, fb = tid >> 7;      // fb 0/1 covers f 0..63 / 64..127
        #pragma unroll
        for (int j8 = 0; j8 < 8; ++j8) {
            int f0 = fb * 64 + j8 * 8;
            unsigned pk[4];
            #pragma unroll
            for (int p = 0; p < 4; ++p) {
                float lo = W[(size_t)(f0 + 2 * p) * 128 + ch];
                float hi = W[(size_t)(f0 + 2 * p + 1) * 128 + ch];
                pk[p] = f2bf(lo) | (f2bf(hi) << 16);
            }
            int bcol = (f0 * 2) ^ ((ch & 7) << 4);
            *(uint4*)&Wt[ch * 64 + (bcol >> 2)] = *(uint4*)pk;
        }
    }
    __syncthreads();
    int lane = tid & 63, w = tid >> 6;
    int col = lane & 15, quad = lane >> 4;
    int nodebase = blockIdx.x * 128 + w * 32;
    // A-frags: lane holds x[node = sub*16+col][k = kk*32 + quad*8 + j]
    bf16x8 a[2][4];
    #pragma unroll
    for (int s = 0; s < 2; ++s) {
        int node = nodebase + s * 16 + col;
        const float* xr = x + (size_t)node * 128;
        bool v = node < n;
        #pragma unroll
        for (int kk = 0; kk < 4; ++kk) {
            float4 lo = v ? *(const float4*)&xr[kk * 32 + quad * 8]
                          : make_float4(0.f, 0.f, 0.f, 0.f);
            float4 hi = v ? *(const float4*)&xr[kk * 32 + quad * 8 + 4]
                          : make_float4(0.f, 0.f, 0.f, 0.f);
            unsigned pk[4];
            pk[0] = f2bf(lo.x) | (f2bf(lo.y) << 16);
            pk[1] = f2bf(lo.z) | (f2bf(lo.w) << 16);
            pk[2] = f2bf(hi.x) | (f2bf(hi.y) << 16);
            pk[3] = f2bf(hi.z) | (f2bf(hi.w) << 16);
            a[s][kk] = *(bf16x8*)pk;
        }
    }
    f32x4 acc[2][8] = {};
    #pragma unroll
    for (int c = 0; c < 8; ++c) {
        int brow = c * 16 + col;
        bf16x8 b[4];
        #pragma unroll
        for (int kk = 0; kk < 4; ++kk) {
            int bcol = (kk * 64 + quad * 16) ^ ((brow & 7) << 4);
            b[kk] = *(bf16x8*)&Wt[brow * 64 + (bcol >> 2)];
        }
        #pragma unroll
        for (int s = 0; s < 2; ++s)
            #pragma unroll
            for (int kk = 0; kk < 4; ++kk)
                acc[s][c] = __builtin_amdgcn_mfma_f32_16x16x32_bf16(a[s][kk], b[kk], acc[s][c], 0, 0, 0);
    }
    // epilogue: pack h to bf16 pairs + fused attention coefficients
    float aS[8], aD[8];
    #pragma unroll
    for (int c = 0; c < 8; ++c) { aS[c] = att_s[c * 16 + col]; aD[c] = att_d[c * 16 + col]; }
    #pragma unroll
    for (int s = 0; s < 2; ++s) {
        #pragma unroll
        for (int c = 0; c < 8; ++c) {
            #pragma unroll
            for (int r = 0; r < 4; ++r) {
                float own = acc[s][c][r];
                float par = SWZ_F(own, 0x041F);        // lane ^ 1
                int node = nodebase + s * 16 + quad * 4 + r;
                if (!(lane & 1) && node < n)
                    hp[(size_t)node * 64 + c * 8 + (col >> 1)] =
                        f2bf(own) | (f2bf(par) << 16);
            }
        }
        #pragma unroll
        for (int h = 0; h < 4; ++h) {
            #pragma unroll
            for (int r = 0; r < 4; ++r) {
                float ps = acc[s][2 * h][r] * aS[2 * h] + acc[s][2 * h + 1][r] * aS[2 * h + 1];
                float pd = acc[s][2 * h][r] * aD[2 * h] + acc[s][2 * h + 1][r] * aD[2 * h + 1];
                ps += SWZ_F(ps, 0x041F); pd += SWZ_F(pd, 0x041F);
                ps += SWZ_F(ps, 0x081F); pd += SWZ_F(pd, 0x081F);
                ps += SWZ_F(ps, 0x101F); pd += SWZ_F(pd, 0x101F);
                ps += SWZ_F(ps, 0x201F); pd += SWZ_F(pd, 0x201F);
                int node = nodebase + s * 16 + quad * 4 + r;
                if (col == 0 && node < n) {
                    as_[(size_t)node * 4 + h] = ps;
                    ad_[(size_t)node * 4 + h] = pd;
                }
            }
        }
    }
}

// Layer2 GEMM via MFMA bf16: [N,128(bf16-packed)]x[128,64].
__global__ __launch_bounds__(256) void gemm2_kernel(
        const unsigned* __restrict__ xp, const float* __restrict__ W,
        const float* __restrict__ att_s, const float* __restrict__ att_d,
        unsigned* __restrict__ hp, float* __restrict__ as_, float* __restrict__ ad_, int n) {
    __shared__ uint4 WtS[1024];                 // 16 KB: Wt[64ch][128k] bf16
    unsigned* Wt = (unsigned*)WtS;
    int tid = threadIdx.x;
    {   // stage W2^T
        int ch = tid & 63, fb = tid >> 6;       // fb 0..3 covers f-blocks of 32
        #pragma unroll
        for (int j8 = 0; j8 < 4; ++j8) {
            int f0 = fb * 32 + j8 * 8;
            unsigned pk[4];
            #pragma unroll
            for (int p = 0; p < 4; ++p) {
                float lo = W[(size_t)(f0 + 2 * p) * 64 + ch];
                float hi = W[(size_t)(f0 + 2 * p + 1) * 64 + ch];
                pk[p] = f2bf(lo) | (f2bf(hi) << 16);
            }
            int bcol = (f0 * 2) ^ ((ch & 7) << 4);
            *(uint4*)&Wt[ch * 64 + (bcol >> 2)] = *(uint4*)pk;
        }
    }
    __syncthreads();
    int lane = tid & 63, w = tid >> 6;
    int col = lane & 15, quad = lane >> 4;
    int nodebase = blockIdx.x * 128 + w * 32;
    bf16x8 a[2][4];
    #pragma unroll
    for (int s = 0; s < 2; ++s) {
        int node = nodebase + s * 16 + col;
        bool v = node < n;
        #pragma unroll
        for (int kk = 0; kk < 4; ++kk) {
            uint4 u = v ? *(const uint4*)&xp[(size_t)node * 64 + kk * 16 + quad * 4]
                        : make_uint4(0, 0, 0, 0);
            a[s][kk] = *(bf16x8*)&u;
        }
    }
    f32x4 acc[2][4] = {};
    #pragma unroll
    for (int c = 0; c < 4; ++c) {
        int brow = c * 16 + col;
        bf16x8 b[4];
        #pragma unroll
        for (int kk = 0; kk < 4; ++kk) {
            int bcol = (kk * 64 + quad * 16) ^ ((brow & 7) << 4);
            b[kk] = *(bf16x8*)&Wt[brow * 64 + (bcol >> 2)];
        }
        #pragma unroll
        for (int s = 0; s < 2; ++s)
            #pragma unroll
            for (int kk = 0; kk < 4; ++kk)
                acc[s][c] = __builtin_amdgcn_mfma_f32_16x16x32_bf16(a[s][kk], b[kk], acc[s][c], 0, 0, 0);
    }
    float aS[4], aD[4];
    #pragma unroll
    for (int c = 0; c < 4; ++c) { aS[c] = att_s[c * 16 + col]; aD[c] = att_d[c * 16 + col]; }
    #pragma unroll
    for (int s = 0; s < 2; ++s) {
        #pragma unroll
        for (int c = 0; c < 4; ++c) {
            #pragma unroll
            for (int r = 0; r < 4; ++r) {
                float own = acc[s][c][r];
                float par = SWZ_F(own, 0x041F);
                int node = nodebase + s * 16 + quad * 4 + r;
                if (!(lane & 1) && node < n)
                    hp[(size_t)node * 32 + c * 8 + (col >> 1)] =
                        f2bf(own) | (f2bf(par) << 16);
            }
        }
        #pragma unroll
        for (int r = 0; r < 4; ++r) {
            float ps = 0.f, pd = 0.f;
            #pragma unroll
            for (int c = 0; c < 4; ++c) {
                ps = fmaf(acc[s][c][r], aS[c], ps);
                pd = fmaf(acc[s][c][r], aD[c], pd);
            }
            ps += SWZ_F(ps, 0x041F); pd += SWZ_F(pd, 0x041F);
            ps += SWZ_F(ps, 0x081F); pd += SWZ_F(pd, 0x081F);
            ps += SWZ_F(ps, 0x101F); pd += SWZ_F(pd, 0x101F);
            ps += SWZ_F(ps, 0x201F); pd += SWZ_F(pd, 0x201F);
            int node = nodebase + s * 16 + quad * 4 + r;
            if (col == 0 && node < n) { as_[node] = ps; ad_[node] = pd; }
        }
    }
}

// ---------------------------------------------------------------------------
// Aggregation layer1: wave per dst node, lane owns channels (2l, 2l+1),
// head = lane>>4. 32-edge chunks mirrored into both 32-lane halves; weights
// computed once per (edge, head) in lane layout (edge&15 | head<<4) and
// broadcast via single-instruction ds_swizzle. Branch-free 8-edge groups.
#define A1_G8(B, K0) { \
    int t0 = SWZ_I(myc, (((B)+(K0)+0)<<5)); \
    int t1 = SWZ_I(myc, (((B)+(K0)+1)<<5)); \
    int t2 = SWZ_I(myc, (((B)+(K0)+2)<<5)); \
    int t3 = SWZ_I(myc, (((B)+(K0)+3)<<5)); \
    int t4 = SWZ_I(myc, (((B)+(K0)+4)<<5)); \
    int t5 = SWZ_I(myc, (((B)+(K0)+5)<<5)); \
    int t6 = SWZ_I(myc, (((B)+(K0)+6)<<5)); \
    int t7 = SWZ_I(myc, (((B)+(K0)+7)<<5)); \
    unsigned v0 = hp[(size_t)t0 * 64 + lane]; \
    unsigned v1 = hp[(size_t)t1 * 64 + lane]; \
    unsigned v2 = hp[(size_t)t2 * 64 + lane]; \
    unsigned v3 = hp[(size_t)t3 * 64 + lane]; \
    unsigned v4 = hp[(size_t)t4 * 64 + lane]; \
    unsigned v5 = hp[(size_t)t5 * 64 + lane]; \
    unsigned v6 = hp[(size_t)t6 * 64 + lane]; \
    unsigned v7 = hp[(size_t)t7 * 64 + lane]; \
    float q0 = SWZ_F(ew, ((((K0)+0)<<5)|0x10)); \
    float q1 = SWZ_F(ew, ((((K0)+1)<<5)|0x10)); \
    float q2 = SWZ_F(ew, ((((K0)+2)<<5)|0x10)); \
    float q3 = SWZ_F(ew, ((((K0)+3)<<5)|0x10)); \
    float q4 = SWZ_F(ew, ((((K0)+4)<<5)|0x10)); \
    float q5 = SWZ_F(ew, ((((K0)+5)<<5)|0x10)); \
    float q6 = SWZ_F(ew, ((((K0)+6)<<5)|0x10)); \
    float q7 = SWZ_F(ew, ((((K0)+7)<<5)|0x10)); \
    s += q0; acc0 = fmaf(q0, bflo(v0), acc0); acc1 = fmaf(q0, bfhi(v0), acc1); \
    s += q1; acc0 = fmaf(q1, bflo(v1), acc0); acc1 = fmaf(q1, bfhi(v1), acc1); \
    s += q2; acc0 = fmaf(q2, bflo(v2), acc0); acc1 = fmaf(q2, bfhi(v2), acc1); \
    s += q3; acc0 = fmaf(q3, bflo(v3), acc0); acc1 = fmaf(q3, bfhi(v3), acc1); \
    s += q4; acc0 = fmaf(q4, bflo(v4), acc0); acc1 = fmaf(q4, bfhi(v4), acc1); \
    s += q5; acc0 = fmaf(q5, bflo(v5), acc0); acc1 = fmaf(q5, bfhi(v5), acc1); \
    s += q6; acc0 = fmaf(q6, bflo(v6), acc0); acc1 = fmaf(q6, bfhi(v6), acc1); \
    s += q7; acc0 = fmaf(q7, bflo(v7), acc0); acc1 = fmaf(q7, bfhi(v7), acc1); }

#define A1_SUB(B) { \
    int sspec = SWZ_I(myc, (((B)<<5) | 0x0F)); \
    float ee_ = as_[(size_t)sspec * 4 + head] + adv; \
    ee_ = fmaxf(ee_, 0.2f * ee_); \
    float ew = ((cb + (B) + (lane & 15)) < end) ? __expf(ee_) : 0.f; \
    A1_G8(B, 0) \
    if (m > (B) + 8) A1_G8(B, 8) }

__global__ __launch_bounds__(256) void agg1_kernel(
        const unsigned* __restrict__ hp, const float* __restrict__ as_,
        const float* __restrict__ ad_, const int* __restrict__ row_ptr,
        const int* __restrict__ col, const float* __restrict__ bias,
        unsigned* __restrict__ outp, int n) {
    int wid = (blockIdx.x * 256 + threadIdx.x) >> 6;
    int lane = threadIdx.x & 63;
    if (wid >= n) return;
    int node = wid;
    int head = lane >> 4;                   // head of channels (2l, 2l+1)
    float adv = ad_[(size_t)node * 4 + head];
    float e0 = as_[(size_t)node * 4 + head] + adv;
    e0 = fmaxf(e0, 0.2f * e0);
    float w0 = __expf(e0);
    float s = w0;
    unsigned u0 = hp[(size_t)node * 64 + lane];
    float acc0 = w0 * bflo(u0), acc1 = w0 * bfhi(u0);
    int beg = row_ptr[node], end = row_ptr[node + 1];
    for (int cb = beg; cb < end; cb += 32) {
        int m = end - cb; if (m > 32) m = 32;
        int ci = cb + (lane & 31);
        int myc = col[(ci < end) ? ci : (end - 1)];   // mirrored into both halves
        A1_SUB(0)
        if (m > 16) A1_SUB(16)
    }
    float inv = 1.0f / (s + 1e-16f);
    float2 b = *(const float2*)&bias[lane * 2];
    outp[(size_t)node * 64 + lane] =
        f2bf(acc0 * inv + b.x) | (f2bf(acc1 * inv + b.y) << 16);
}

// Aggregation layer2: wave per dst node; halves process even/odd edges.
#define A2_G4(K0) { \
    int t0 = SWZ_I(myc, (((K0)+0)<<5)); \
    int t1 = SWZ_I(myc, (((K0)+1)<<5)); \
    int t2 = SWZ_I(myc, (((K0)+2)<<5)); \
    int t3 = SWZ_I(myc, (((K0)+3)<<5)); \
    unsigned v0 = hp[(size_t)t0 * 32 + wrd]; \
    unsigned v1 = hp[(size_t)t1 * 32 + wrd]; \
    unsigned v2 = hp[(size_t)t2 * 32 + wrd]; \
    unsigned v3 = hp[(size_t)t3 * 32 + wrd]; \
    float q0 = SWZ_F(ew, (((K0)+0)<<5)); \
    float q1 = SWZ_F(ew, (((K0)+1)<<5)); \
    float q2 = SWZ_F(ew, (((K0)+2)<<5)); \
    float q3 = SWZ_F(ew, (((K0)+3)<<5)); \
    s += q0; acc0 = fmaf(q0, bflo(v0), acc0); acc1 = fmaf(q0, bfhi(v0), acc1); \
    s += q1; acc0 = fmaf(q1, bflo(v1), acc0); acc1 = fmaf(q1, bfhi(v1), acc1); \
    s += q2; acc0 = fmaf(q2, bflo(v2), acc0); acc1 = fmaf(q2, bfhi(v2), acc1); \
    s += q3; acc0 = fmaf(q3, bflo(v3), acc0); acc1 = fmaf(q3, bfhi(v3), acc1); }

__global__ __launch_bounds__(256) void agg2_kernel(
        const unsigned* __restrict__ hp, const float* __restrict__ as_,
        const float* __restrict__ ad_, const int* __restrict__ row_ptr,
        const int* __restrict__ col, const float* __restrict__ bias,
        float* __restrict__ out, int n) {
    int wid = (blockIdx.x * 256 + threadIdx.x) >> 6;
    int lane = threadIdx.x & 63;
    if (wid >= n) return;
    int node = wid;
    int half = lane >> 5, wrd = lane & 31;
    float adv = ad_[node];
    float s = 0.f, acc0 = 0.f, acc1 = 0.f;
    {
        float e = as_[node] + adv; e = fmaxf(e, 0.2f * e);
        float w = __expf(e);
        if (half == 0) {
            unsigned u = hp[(size_t)node * 32 + wrd];
            s = w; acc0 = w * bflo(u); acc1 = w * bfhi(u);
        }
    }
    int beg = row_ptr[node], end = row_ptr[node + 1];
    for (int cb = beg; cb < end; cb += 64) {
        int m = end - cb; if (m > 64) m = 64;
        int idx = cb + 2 * (lane & 31) + half;
        int myc = col[(idx < end) ? idx : (end - 1)];
        float ee = as_[myc] + adv; ee = fmaxf(ee, 0.2f * ee);
        float ew = (idx < end) ? __expf(ee) : 0.f;
        A2_G4(0)
        if (m > 8)  A2_G4(4)
        if (m > 16) A2_G4(8)
        if (m > 24) A2_G4(12)
        if (m > 32) {
            A2_G4(16)
            if (m > 40) A2_G4(20)
            if (m > 48) A2_G4(24)
            if (m > 56) A2_G4(28)
        }
    }
    s += __shfl_xor(s, 32);
    acc0 += __shfl_xor(acc0, 32);
    acc1 += __shfl_xor(acc1, 32);
    if (half == 0) {
        float inv = 1.0f / (s + 1e-16f);
        float2 b = *(const float2*)&bias[wrd * 2];
        *(float2*)&out[(size_t)node * 64 + wrd * 2] =
            make_float2(acc0 * inv + b.x, acc1 * inv + b.y);
    }
}

// ---------------------------------------------------------------------------
extern "C" void kernel_launch(void* const* d_in, const int* in_sizes, int n_in,
                              void* d_out, int out_size, void* d_ws, size_t ws_size,
                              hipStream_t stream) {
    const float* inp   = (const float*)d_in[0];
    const int*   ei    = (const int*)d_in[1];
    const float* W1    = (const float*)d_in[2];
    const float* atts1 = (const float*)d_in[3];
    const float* attd1 = (const float*)d_in[4];
    const float* bias1 = (const float*)d_in[5];
    const float* W2    = (const float*)d_in[6];
    const float* atts2 = (const float*)d_in[7];
    const float* attd2 = (const float*)d_in[8];
    const float* bias2 = (const float*)d_in[9];
    float* out = (float*)d_out;

    const int N = N_NODES;
    const int E = in_sizes[1] / 2;

    unsigned* h1p = (unsigned*)d_ws;               // N*64 uints (layer2 reuses N*32)
    unsigned* x1p = h1p + (size_t)N * 64;          // N*64 uints (bf16-packed x1)
    float* as1 = (float*)(x1p + (size_t)N * 64);   // N*4
    float* ad1 = as1 + (size_t)N * 4;              // N*4
    int* cnt      = (int*)(ad1 + (size_t)N * 4);   // N
    int* row_ptr  = cnt + N;                       // N+1
    int* bsum     = row_ptr + N + 1;               // 128
    int* flag     = bsum + 128;                    // 1
    int* col      = flag + 1;                      // E
    int* rank     = (int*)x1p;                     // E ints, aliases x1p (dead before agg1)

    hipMemsetAsync(cnt, 0, N * sizeof(int), stream);
    detect_kernel<<<1, 64, 0, stream>>>(ei, flag);

    int nb = (N + SCAN_BLOCK - 1) / SCAN_BLOCK;
    int ethreads = (E + EPB - 1) / EPB;
    count_kernel<<<(ethreads + 255) / 256, 256, 0, stream>>>(ei, flag, cnt, rank, E);
    scanA_kernel<<<nb, SCAN_BLOCK, 0, stream>>>(cnt, row_ptr, bsum, N);
    scanB_kernel<<<1, 128, 0, stream>>>(bsum, nb, row_ptr + N, E);
    scanC_kernel<<<nb, SCAN_BLOCK, 0, stream>>>(row_ptr, bsum, N);
    fill_kernel<<<(ethreads + 255) / 256, 256, 0, stream>>>(ei, flag, row_ptr, rank, col, E);

    // layer 1
    gemm1_kernel<<<(N + 127) / 128, 256, 0, stream>>>(inp, W1, atts1, attd1, h1p, as1, ad1, N);
    agg1_kernel<<<(N + 3) / 4, 256, 0, stream>>>(h1p, as1, ad1, row_ptr, col, bias1, x1p, N);

    // layer 2 (h2p aliases h1p; as2/ad2 alias as1/ad1)
    gemm2_kernel<<<(N + 127) / 128, 256, 0, stream>>>(x1p, W2, atts2, attd2, h1p, as1, ad1, N);
    agg2_kernel<<<(N + 3) / 4, 256, 0, stream>>>(h1p, as1, ad1, row_ptr, col, bias2, out, N);
}